// Round 1
// baseline (774.962 us; speedup 1.0000x reference)
//
#include <hip/hip_runtime.h>
#include <math.h>

#define HDIM 128
#define ROWS 16
#define LN_EPS 1e-5f

// ---------------- CSR build ----------------

__global__ void count_kernel(const int* __restrict__ dst, int* __restrict__ counts, int E) {
  int e = blockIdx.x * blockDim.x + threadIdx.x;
  if (e < E) atomicAdd(&counts[dst[e]], 1);
}

__global__ void dinv_kernel(const int* __restrict__ counts, float* __restrict__ dinv, int n) {
  int v = blockIdx.x * blockDim.x + threadIdx.x;
  if (v < n) dinv[v] = rsqrtf((float)(counts[v] + 1));  // +1 self-loop => deg >= 1
}

__global__ __launch_bounds__(1024) void scan_kernel(const int* __restrict__ counts,
                                                    int* __restrict__ rowptr,
                                                    int* __restrict__ cursor, int n) {
  __shared__ int sh[1024];
  int tid = threadIdx.x;
  int chunk = (n + 1023) >> 10;
  int start = tid * chunk;
  int end = start + chunk;
  if (end > n) end = n;
  int sum = 0;
  for (int i = start; i < end; ++i) sum += counts[i];
  sh[tid] = sum;
  __syncthreads();
  for (int off = 1; off < 1024; off <<= 1) {
    int v = (tid >= off) ? sh[tid - off] : 0;
    __syncthreads();
    sh[tid] += v;
    __syncthreads();
  }
  int prefix = (tid == 0) ? 0 : sh[tid - 1];
  for (int i = start; i < end; ++i) {
    rowptr[i] = prefix;
    cursor[i] = prefix;
    prefix += counts[i];
  }
  if (tid == 1023) rowptr[n] = sh[1023];
}

__global__ void fill_kernel(const int* __restrict__ src, const int* __restrict__ dst,
                            int* __restrict__ cursor, const float* __restrict__ dinv,
                            int* __restrict__ csr_src, float* __restrict__ csr_w, int E) {
  int e = blockIdx.x * blockDim.x + threadIdx.x;
  if (e < E) {
    int s = src[e], d = dst[e];
    int pos = atomicAdd(&cursor[d], 1);
    csr_src[pos] = s;
    csr_w[pos] = dinv[s] * dinv[d];
  }
}

// ---------------- Layer 1: aggregate 6-wide, then 6->128 GEMM + LN + ReLU ----------------

__global__ __launch_bounds__(64) void layer1_kernel(
    const float* __restrict__ x, const float* __restrict__ W1,
    const float* __restrict__ b1, const float* __restrict__ gam,
    const float* __restrict__ bet, const int* __restrict__ rowptr,
    const int* __restrict__ csr_src, const float* __restrict__ csr_w,
    const float* __restrict__ dinv, float* __restrict__ hout, int n) {
  int v = blockIdx.x;
  int lane = threadIdx.x;
  float a[6] = {0.f, 0.f, 0.f, 0.f, 0.f, 0.f};
  int e1 = rowptr[v + 1];
  for (int e = rowptr[v] + lane; e < e1; e += 64) {
    int s = csr_src[e];
    float w = csr_w[e];
#pragma unroll
    for (int j = 0; j < 6; ++j) a[j] = fmaf(x[s * 6 + j], w, a[j]);
  }
  if (lane == 0) {
    float dv = dinv[v];
    float w = dv * dv;
#pragma unroll
    for (int j = 0; j < 6; ++j) a[j] = fmaf(x[v * 6 + j], w, a[j]);
  }
#pragma unroll
  for (int off = 32; off >= 1; off >>= 1) {
#pragma unroll
    for (int j = 0; j < 6; ++j) a[j] += __shfl_xor(a[j], off, 64);
  }
  int f0 = lane, f1 = lane + 64;
  float o0 = b1[f0], o1 = b1[f1];
#pragma unroll
  for (int j = 0; j < 6; ++j) {
    o0 = fmaf(a[j], W1[j * HDIM + f0], o0);
    o1 = fmaf(a[j], W1[j * HDIM + f1], o1);
  }
  float s = o0 + o1, q = o0 * o0 + o1 * o1;
#pragma unroll
  for (int off = 32; off >= 1; off >>= 1) {
    s += __shfl_xor(s, off, 64);
    q += __shfl_xor(q, off, 64);
  }
  float m = s * (1.0f / HDIM);
  float var = fmaxf(q * (1.0f / HDIM) - m * m, 0.f);
  float rs = rsqrtf(var + LN_EPS);
  float y0 = fmaxf(fmaf((o0 - m) * rs, gam[f0], bet[f0]), 0.f);
  float y1 = fmaxf(fmaf((o1 - m) * rs, gam[f1], bet[f1]), 0.f);
  hout[v * HDIM + f0] = y0;
  hout[v * HDIM + f1] = y1;
}

// ---------------- Layers 2/3: aggregate 128-wide -> 128x128 GEMM + LN (+ReLU) ----------------

#define FMA4(A, S, Wv)            \
  A.x = fmaf(S, Wv.x, A.x);       \
  A.y = fmaf(S, Wv.y, A.y);       \
  A.z = fmaf(S, Wv.z, A.z);       \
  A.w = fmaf(S, Wv.w, A.w);

__global__ __launch_bounds__(256) void layer_kernel(
    const float* __restrict__ hin, const float* __restrict__ W,
    const float* __restrict__ bias, const float* __restrict__ gam,
    const float* __restrict__ bet, const int* __restrict__ rowptr,
    const int* __restrict__ csr_src, const float* __restrict__ csr_w,
    const float* __restrict__ dinv, float* __restrict__ hout, int n, int do_relu) {
  __shared__ float s_agg[ROWS][HDIM];  // 8 KB
  int tid = threadIdx.x;
  int v0 = blockIdx.x * ROWS;

  // Phase A: aggregation. 128 f-threads x 2 halves; coalesced 512B row gathers.
  {
    int f = tid & (HDIM - 1);
    int half = tid >> 7;
    for (int i = 0; i < ROWS / 2; ++i) {
      int r = half * (ROWS / 2) + i;
      int v = v0 + r;
      if (v < n) {
        float dv = dinv[v];
        float acc = hin[v * HDIM + f] * dv * dv;  // self-loop
        int e1 = rowptr[v + 1];
        for (int e = rowptr[v]; e < e1; ++e) {
          acc = fmaf(hin[csr_src[e] * HDIM + f], csr_w[e], acc);
        }
        s_agg[r][f] = acc;
      } else {
        s_agg[r][f] = 0.f;
      }
    }
  }
  __syncthreads();

  // Phase B: GEMM, 2 rows x 4 cols per thread.
  int colg = tid & 31;
  int rowg = tid >> 5;  // 0..7 -> contiguous 32-lane segment within a wave
  int f4 = colg << 2;
  int r0 = rowg << 1, r1 = r0 + 1;
  float4 bv = *(const float4*)&bias[f4];
  float4 acc0 = bv, acc1 = bv;
  const float4* a0p = (const float4*)s_agg[r0];
  const float4* a1p = (const float4*)s_agg[r1];
#pragma unroll 8
  for (int kc = 0; kc < HDIM / 4; ++kc) {
    float4 a0 = a0p[kc];
    float4 a1 = a1p[kc];
    const float* wp = &W[(kc << 2) * HDIM + f4];
    float4 w0 = *(const float4*)wp;
    float4 w1 = *(const float4*)(wp + HDIM);
    float4 w2 = *(const float4*)(wp + 2 * HDIM);
    float4 w3 = *(const float4*)(wp + 3 * HDIM);
    FMA4(acc0, a0.x, w0) FMA4(acc0, a0.y, w1) FMA4(acc0, a0.z, w2) FMA4(acc0, a0.w, w3)
    FMA4(acc1, a1.x, w0) FMA4(acc1, a1.y, w1) FMA4(acc1, a1.z, w2) FMA4(acc1, a1.w, w3)
  }

  // LayerNorm: each row lives in one 32-lane segment -> width-32 butterfly.
  float s0 = acc0.x + acc0.y + acc0.z + acc0.w;
  float q0 = acc0.x * acc0.x + acc0.y * acc0.y + acc0.z * acc0.z + acc0.w * acc0.w;
  float s1 = acc1.x + acc1.y + acc1.z + acc1.w;
  float q1 = acc1.x * acc1.x + acc1.y * acc1.y + acc1.z * acc1.z + acc1.w * acc1.w;
#pragma unroll
  for (int off = 16; off >= 1; off >>= 1) {
    s0 += __shfl_xor(s0, off, 32);
    q0 += __shfl_xor(q0, off, 32);
    s1 += __shfl_xor(s1, off, 32);
    q1 += __shfl_xor(q1, off, 32);
  }
  float inv = 1.0f / HDIM;
  float m0 = s0 * inv, m1 = s1 * inv;
  float rs0 = rsqrtf(fmaxf(q0 * inv - m0 * m0, 0.f) + LN_EPS);
  float rs1 = rsqrtf(fmaxf(q1 * inv - m1 * m1, 0.f) + LN_EPS);
  float4 gv = *(const float4*)&gam[f4];
  float4 bev = *(const float4*)&bet[f4];
  float4 y0, y1;
  y0.x = fmaf((acc0.x - m0) * rs0, gv.x, bev.x);
  y0.y = fmaf((acc0.y - m0) * rs0, gv.y, bev.y);
  y0.z = fmaf((acc0.z - m0) * rs0, gv.z, bev.z);
  y0.w = fmaf((acc0.w - m0) * rs0, gv.w, bev.w);
  y1.x = fmaf((acc1.x - m1) * rs1, gv.x, bev.x);
  y1.y = fmaf((acc1.y - m1) * rs1, gv.y, bev.y);
  y1.z = fmaf((acc1.z - m1) * rs1, gv.z, bev.z);
  y1.w = fmaf((acc1.w - m1) * rs1, gv.w, bev.w);
  if (do_relu) {
    y0.x = fmaxf(y0.x, 0.f); y0.y = fmaxf(y0.y, 0.f);
    y0.z = fmaxf(y0.z, 0.f); y0.w = fmaxf(y0.w, 0.f);
    y1.x = fmaxf(y1.x, 0.f); y1.y = fmaxf(y1.y, 0.f);
    y1.z = fmaxf(y1.z, 0.f); y1.w = fmaxf(y1.w, 0.f);
  }
  if (v0 + r0 < n) *(float4*)&hout[(v0 + r0) * HDIM + f4] = y0;
  if (v0 + r1 < n) *(float4*)&hout[(v0 + r1) * HDIM + f4] = y1;
}

// ---------------- Head: 128 -> 64 (ReLU) -> 1, sigmoid ----------------

__global__ __launch_bounds__(64) void head_kernel(
    const float* __restrict__ h, const float* __restrict__ rW1,
    const float* __restrict__ rb1, const float* __restrict__ rW2,
    const float* __restrict__ rb2, float* __restrict__ out, int n) {
  __shared__ float sh[HDIM];
  int v = blockIdx.x;
  int j = threadIdx.x;
  sh[j] = h[v * HDIM + j];
  sh[j + 64] = h[v * HDIM + j + 64];
  __syncthreads();
  float acc = rb1[j];
#pragma unroll 8
  for (int k = 0; k < HDIM; ++k) acc = fmaf(sh[k], rW1[k * 64 + j], acc);
  acc = fmaxf(acc, 0.f);
  float p = acc * rW2[j];
#pragma unroll
  for (int off = 32; off >= 1; off >>= 1) p += __shfl_xor(p, off, 64);
  if (j == 0) out[v] = 1.0f / (1.0f + expf(-(p + rb2[0])));
}

// ---------------- Launch ----------------

extern "C" void kernel_launch(void* const* d_in, const int* in_sizes, int n_in,
                              void* d_out, int out_size, void* d_ws, size_t ws_size,
                              hipStream_t stream) {
  const float* x   = (const float*)d_in[0];
  const int*  eidx = (const int*)d_in[1];   // int32 on device (jax x64 disabled)
  const float* W1  = (const float*)d_in[2];
  const float* b1  = (const float*)d_in[3];
  const float* W2  = (const float*)d_in[4];
  const float* b2  = (const float*)d_in[5];
  const float* W3  = (const float*)d_in[6];
  const float* b3  = (const float*)d_in[7];
  const float* g1  = (const float*)d_in[8];
  const float* be1 = (const float*)d_in[9];
  const float* g2  = (const float*)d_in[10];
  const float* be2 = (const float*)d_in[11];
  const float* g3  = (const float*)d_in[12];
  const float* be3 = (const float*)d_in[13];
  const float* rW1 = (const float*)d_in[14];
  const float* rb1 = (const float*)d_in[15];
  const float* rW2 = (const float*)d_in[16];
  const float* rb2 = (const float*)d_in[17];

  int N = in_sizes[0] / 6;
  int E = in_sizes[1] / 2;
  const int* srcp = eidx;
  const int* dstp = eidx + E;
  float* out = (float*)d_out;

  char* p = (char*)d_ws;
  auto alloc = [&](size_t bytes) -> void* {
    void* r = (void*)p;
    p += (bytes + 255) & ~(size_t)255;
    return r;
  };
  int*   counts  = (int*)alloc((size_t)N * 4);
  int*   rowptr  = (int*)alloc((size_t)(N + 1) * 4);
  int*   cursor  = (int*)alloc((size_t)N * 4);
  float* dinvp   = (float*)alloc((size_t)N * 4);
  int*   csr_src = (int*)alloc((size_t)E * 4);
  float* csr_w   = (float*)alloc((size_t)E * 4);
  float* h_a     = (float*)alloc((size_t)N * HDIM * 4);
  float* h_b     = (float*)alloc((size_t)N * HDIM * 4);

  hipMemsetAsync(counts, 0, (size_t)N * 4, stream);
  count_kernel<<<(E + 255) / 256, 256, 0, stream>>>(dstp, counts, E);
  dinv_kernel<<<(N + 255) / 256, 256, 0, stream>>>(counts, dinvp, N);
  scan_kernel<<<1, 1024, 0, stream>>>(counts, rowptr, cursor, N);
  fill_kernel<<<(E + 255) / 256, 256, 0, stream>>>(srcp, dstp, cursor, dinvp, csr_src, csr_w, E);

  layer1_kernel<<<N, 64, 0, stream>>>(x, W1, b1, g1, be1, rowptr, csr_src, csr_w, dinvp, h_a, N);
  int nb = (N + ROWS - 1) / ROWS;
  layer_kernel<<<nb, 256, 0, stream>>>(h_a, W2, b2, g2, be2, rowptr, csr_src, csr_w, dinvp, h_b, N, 1);
  layer_kernel<<<nb, 256, 0, stream>>>(h_b, W3, b3, g3, be3, rowptr, csr_src, csr_w, dinvp, h_a, N, 0);
  head_kernel<<<N, 64, 0, stream>>>(h_a, rW1, rb1, rW2, rb2, out, N);
}

// Round 2
// 656.474 us; speedup vs baseline: 1.1805x; 1.1805x over previous
//
#include <hip/hip_runtime.h>
#include <math.h>

#define HDIM 128
#define ROWS 16
#define LN_EPS 1e-5f

// ---------------- CSR build ----------------

__global__ void count_kernel(const int* __restrict__ dst, int* __restrict__ counts, int E) {
  int e = blockIdx.x * blockDim.x + threadIdx.x;
  if (e < E) atomicAdd(&counts[dst[e]], 1);
}

__global__ void dinv_kernel(const int* __restrict__ counts, float* __restrict__ dinv, int n) {
  int v = blockIdx.x * blockDim.x + threadIdx.x;
  if (v < n) dinv[v] = rsqrtf((float)(counts[v] + 1));  // +1 self-loop => deg >= 1
}

__global__ __launch_bounds__(1024) void scan_kernel(const int* __restrict__ counts,
                                                    int* __restrict__ rowptr,
                                                    int* __restrict__ cursor, int n) {
  __shared__ int sh[1024];
  int tid = threadIdx.x;
  int chunk = (n + 1023) >> 10;
  int start = tid * chunk;
  int end = start + chunk;
  if (end > n) end = n;
  int sum = 0;
  for (int i = start; i < end; ++i) sum += counts[i];
  sh[tid] = sum;
  __syncthreads();
  for (int off = 1; off < 1024; off <<= 1) {
    int v = (tid >= off) ? sh[tid - off] : 0;
    __syncthreads();
    sh[tid] += v;
    __syncthreads();
  }
  int prefix = (tid == 0) ? 0 : sh[tid - 1];
  for (int i = start; i < end; ++i) {
    rowptr[i] = prefix;
    cursor[i] = prefix;
    prefix += counts[i];
  }
  if (tid == 1023) rowptr[n] = sh[1023];
}

__global__ void fill_kernel(const int* __restrict__ src, const int* __restrict__ dst,
                            int* __restrict__ cursor, const float* __restrict__ dinv,
                            int* __restrict__ csr_src, float* __restrict__ csr_w, int E) {
  int e = blockIdx.x * blockDim.x + threadIdx.x;
  if (e < E) {
    int s = src[e], d = dst[e];
    int pos = atomicAdd(&cursor[d], 1);
    csr_src[pos] = s;
    csr_w[pos] = dinv[s] * dinv[d];
  }
}

// ---------------- Layer 1: aggregate 6-wide, then 6->128 GEMM + LN + ReLU ----------------

__global__ __launch_bounds__(64) void layer1_kernel(
    const float* __restrict__ x, const float* __restrict__ W1,
    const float* __restrict__ b1, const float* __restrict__ gam,
    const float* __restrict__ bet, const int* __restrict__ rowptr,
    const int* __restrict__ csr_src, const float* __restrict__ csr_w,
    const float* __restrict__ dinv, float* __restrict__ hout, int n) {
  int v = blockIdx.x;
  int lane = threadIdx.x;
  float a[6] = {0.f, 0.f, 0.f, 0.f, 0.f, 0.f};
  int e1 = rowptr[v + 1];
  for (int e = rowptr[v] + lane; e < e1; e += 64) {
    int s = csr_src[e];
    float w = csr_w[e];
#pragma unroll
    for (int j = 0; j < 6; ++j) a[j] = fmaf(x[s * 6 + j], w, a[j]);
  }
  if (lane == 0) {
    float dv = dinv[v];
    float w = dv * dv;
#pragma unroll
    for (int j = 0; j < 6; ++j) a[j] = fmaf(x[v * 6 + j], w, a[j]);
  }
#pragma unroll
  for (int off = 32; off >= 1; off >>= 1) {
#pragma unroll
    for (int j = 0; j < 6; ++j) a[j] += __shfl_xor(a[j], off, 64);
  }
  int f0 = lane, f1 = lane + 64;
  float o0 = b1[f0], o1 = b1[f1];
#pragma unroll
  for (int j = 0; j < 6; ++j) {
    o0 = fmaf(a[j], W1[j * HDIM + f0], o0);
    o1 = fmaf(a[j], W1[j * HDIM + f1], o1);
  }
  float s = o0 + o1, q = o0 * o0 + o1 * o1;
#pragma unroll
  for (int off = 32; off >= 1; off >>= 1) {
    s += __shfl_xor(s, off, 64);
    q += __shfl_xor(q, off, 64);
  }
  float m = s * (1.0f / HDIM);
  float var = fmaxf(q * (1.0f / HDIM) - m * m, 0.f);
  float rs = rsqrtf(var + LN_EPS);
  float y0 = fmaxf(fmaf((o0 - m) * rs, gam[f0], bet[f0]), 0.f);
  float y1 = fmaxf(fmaf((o1 - m) * rs, gam[f1], bet[f1]), 0.f);
  hout[v * HDIM + f0] = y0;
  hout[v * HDIM + f1] = y1;
}

// ---------------- Layers 2/3: aggregate -> GEMM + LN (+ReLU | +head) ----------------

#define FMA4(A, S, Wv)            \
  A.x = fmaf(S, Wv.x, A.x);       \
  A.y = fmaf(S, Wv.y, A.y);       \
  A.z = fmaf(S, Wv.z, A.z);       \
  A.w = fmaf(S, Wv.w, A.w);

// mode: 1 = LN+ReLU, store hout. 2 = LN, fused regressor head, store out only.
__global__ __launch_bounds__(256) void layer_kernel(
    const float* __restrict__ hin, const float* __restrict__ W,
    const float* __restrict__ bias, const float* __restrict__ gam,
    const float* __restrict__ bet, const int* __restrict__ rowptr,
    const int* __restrict__ csr_src, const float* __restrict__ csr_w,
    const float* __restrict__ dinv, float* __restrict__ hout,
    const float* __restrict__ rW1, const float* __restrict__ rb1,
    const float* __restrict__ rW2, const float* __restrict__ rb2,
    float* __restrict__ out, int n, int mode) {
  __shared__ float s_agg[ROWS][HDIM];  // 8 KB
  int tid = threadIdx.x;
  int v0 = blockIdx.x * ROWS;

  // Phase A: aggregation, unrolled x4 for 4 outstanding gathers per thread.
  {
    int f = tid & (HDIM - 1);
    int half = tid >> 7;
    for (int i = 0; i < ROWS / 2; ++i) {
      int r = half * (ROWS / 2) + i;
      int v = v0 + r;
      if (v < n) {
        float dv = dinv[v];
        float a0 = hin[v * HDIM + f] * dv * dv;  // self-loop
        float a1 = 0.f, a2 = 0.f, a3 = 0.f;
        int e = rowptr[v];
        int e1 = rowptr[v + 1];
        for (; e + 4 <= e1; e += 4) {
          int s0 = csr_src[e], s1 = csr_src[e + 1];
          int s2 = csr_src[e + 2], s3 = csr_src[e + 3];
          float w0 = csr_w[e], w1 = csr_w[e + 1];
          float w2 = csr_w[e + 2], w3 = csr_w[e + 3];
          float h0 = hin[s0 * HDIM + f];
          float h1 = hin[s1 * HDIM + f];
          float h2 = hin[s2 * HDIM + f];
          float h3 = hin[s3 * HDIM + f];
          a0 = fmaf(h0, w0, a0);
          a1 = fmaf(h1, w1, a1);
          a2 = fmaf(h2, w2, a2);
          a3 = fmaf(h3, w3, a3);
        }
        for (; e < e1; ++e) a0 = fmaf(hin[csr_src[e] * HDIM + f], csr_w[e], a0);
        s_agg[r][f] = (a0 + a1) + (a2 + a3);
      } else {
        s_agg[r][f] = 0.f;
      }
    }
  }
  __syncthreads();

  // Phase B: GEMM, 2 rows x 4 cols per thread.
  int colg = tid & 31;
  int rowg = tid >> 5;  // 0..7 -> contiguous 32-lane segment within a wave
  int f4 = colg << 2;
  int r0 = rowg << 1, r1 = r0 + 1;
  float4 bv = *(const float4*)&bias[f4];
  float4 acc0 = bv, acc1 = bv;
  const float4* a0p = (const float4*)s_agg[r0];
  const float4* a1p = (const float4*)s_agg[r1];
#pragma unroll 8
  for (int kc = 0; kc < HDIM / 4; ++kc) {
    float4 a0 = a0p[kc];
    float4 a1 = a1p[kc];
    const float* wp = &W[(kc << 2) * HDIM + f4];
    float4 w0 = *(const float4*)wp;
    float4 w1 = *(const float4*)(wp + HDIM);
    float4 w2 = *(const float4*)(wp + 2 * HDIM);
    float4 w3 = *(const float4*)(wp + 3 * HDIM);
    FMA4(acc0, a0.x, w0) FMA4(acc0, a0.y, w1) FMA4(acc0, a0.z, w2) FMA4(acc0, a0.w, w3)
    FMA4(acc1, a1.x, w0) FMA4(acc1, a1.y, w1) FMA4(acc1, a1.z, w2) FMA4(acc1, a1.w, w3)
  }

  // LayerNorm: each row lives in one 32-lane segment -> width-32 butterfly.
  float s0 = acc0.x + acc0.y + acc0.z + acc0.w;
  float q0 = acc0.x * acc0.x + acc0.y * acc0.y + acc0.z * acc0.z + acc0.w * acc0.w;
  float s1 = acc1.x + acc1.y + acc1.z + acc1.w;
  float q1 = acc1.x * acc1.x + acc1.y * acc1.y + acc1.z * acc1.z + acc1.w * acc1.w;
#pragma unroll
  for (int off = 16; off >= 1; off >>= 1) {
    s0 += __shfl_xor(s0, off, 32);
    q0 += __shfl_xor(q0, off, 32);
    s1 += __shfl_xor(s1, off, 32);
    q1 += __shfl_xor(q1, off, 32);
  }
  float inv = 1.0f / HDIM;
  float m0 = s0 * inv, m1 = s1 * inv;
  float rs0 = rsqrtf(fmaxf(q0 * inv - m0 * m0, 0.f) + LN_EPS);
  float rs1 = rsqrtf(fmaxf(q1 * inv - m1 * m1, 0.f) + LN_EPS);
  float4 gv = *(const float4*)&gam[f4];
  float4 bev = *(const float4*)&bet[f4];
  float4 y0, y1;
  y0.x = fmaf((acc0.x - m0) * rs0, gv.x, bev.x);
  y0.y = fmaf((acc0.y - m0) * rs0, gv.y, bev.y);
  y0.z = fmaf((acc0.z - m0) * rs0, gv.z, bev.z);
  y0.w = fmaf((acc0.w - m0) * rs0, gv.w, bev.w);
  y1.x = fmaf((acc1.x - m1) * rs1, gv.x, bev.x);
  y1.y = fmaf((acc1.y - m1) * rs1, gv.y, bev.y);
  y1.z = fmaf((acc1.z - m1) * rs1, gv.z, bev.z);
  y1.w = fmaf((acc1.w - m1) * rs1, gv.w, bev.w);

  if (mode == 1) {
    y0.x = fmaxf(y0.x, 0.f); y0.y = fmaxf(y0.y, 0.f);
    y0.z = fmaxf(y0.z, 0.f); y0.w = fmaxf(y0.w, 0.f);
    y1.x = fmaxf(y1.x, 0.f); y1.y = fmaxf(y1.y, 0.f);
    y1.z = fmaxf(y1.z, 0.f); y1.w = fmaxf(y1.w, 0.f);
    if (v0 + r0 < n) *(float4*)&hout[(v0 + r0) * HDIM + f4] = y0;
    if (v0 + r1 < n) *(float4*)&hout[(v0 + r1) * HDIM + f4] = y1;
    return;
  }

  // mode 2: fused regressor head. Round-trip y through s_agg (reuse).
  __syncthreads();  // all phase-B reads of s_agg complete
  *(float4*)&s_agg[r0][f4] = y0;
  *(float4*)&s_agg[r1][f4] = y1;
  __syncthreads();

  // 16 threads per row; each computes 4 of the 64 hidden units.
  int r = tid >> 4;        // 0..15
  int t = tid & 15;        // 0..15
  int j4 = t << 2;         // hidden col group
  float4 hacc = *(const float4*)&rb1[j4];
#pragma unroll 8
  for (int kk = 0; kk < HDIM / 4; ++kk) {
    int kc = (kk + r) & (HDIM / 4 - 1);  // rotate start per row: break LDS same-bank aliasing
    float4 av = ((const float4*)s_agg[r])[kc];
    int kbase = kc << 2;
    float4 w0 = *(const float4*)&rW1[(kbase + 0) * 64 + j4];
    float4 w1 = *(const float4*)&rW1[(kbase + 1) * 64 + j4];
    float4 w2 = *(const float4*)&rW1[(kbase + 2) * 64 + j4];
    float4 w3 = *(const float4*)&rW1[(kbase + 3) * 64 + j4];
    FMA4(hacc, av.x, w0) FMA4(hacc, av.y, w1) FMA4(hacc, av.z, w2) FMA4(hacc, av.w, w3)
  }
  hacc.x = fmaxf(hacc.x, 0.f);
  hacc.y = fmaxf(hacc.y, 0.f);
  hacc.z = fmaxf(hacc.z, 0.f);
  hacc.w = fmaxf(hacc.w, 0.f);
  float4 w2v = *(const float4*)&rW2[j4];
  float p = hacc.x * w2v.x + hacc.y * w2v.y + hacc.z * w2v.z + hacc.w * w2v.w;
#pragma unroll
  for (int off = 8; off >= 1; off >>= 1) p += __shfl_xor(p, off, 16);
  int v = v0 + r;
  if (t == 0 && v < n) out[v] = 1.0f / (1.0f + expf(-(p + rb2[0])));
}

// ---------------- Launch ----------------

extern "C" void kernel_launch(void* const* d_in, const int* in_sizes, int n_in,
                              void* d_out, int out_size, void* d_ws, size_t ws_size,
                              hipStream_t stream) {
  const float* x   = (const float*)d_in[0];
  const int*  eidx = (const int*)d_in[1];
  const float* W1  = (const float*)d_in[2];
  const float* b1  = (const float*)d_in[3];
  const float* W2  = (const float*)d_in[4];
  const float* b2  = (const float*)d_in[5];
  const float* W3  = (const float*)d_in[6];
  const float* b3  = (const float*)d_in[7];
  const float* g1  = (const float*)d_in[8];
  const float* be1 = (const float*)d_in[9];
  const float* g2  = (const float*)d_in[10];
  const float* be2 = (const float*)d_in[11];
  const float* g3  = (const float*)d_in[12];
  const float* be3 = (const float*)d_in[13];
  const float* rW1 = (const float*)d_in[14];
  const float* rb1 = (const float*)d_in[15];
  const float* rW2 = (const float*)d_in[16];
  const float* rb2 = (const float*)d_in[17];

  int N = in_sizes[0] / 6;
  int E = in_sizes[1] / 2;
  const int* srcp = eidx;
  const int* dstp = eidx + E;
  float* out = (float*)d_out;

  char* p = (char*)d_ws;
  auto alloc = [&](size_t bytes) -> void* {
    void* r = (void*)p;
    p += (bytes + 255) & ~(size_t)255;
    return r;
  };
  int*   counts  = (int*)alloc((size_t)N * 4);
  int*   rowptr  = (int*)alloc((size_t)(N + 1) * 4);
  int*   cursor  = (int*)alloc((size_t)N * 4);
  float* dinvp   = (float*)alloc((size_t)N * 4);
  int*   csr_src = (int*)alloc((size_t)E * 4);
  float* csr_w   = (float*)alloc((size_t)E * 4);
  float* h_a     = (float*)alloc((size_t)N * HDIM * 4);
  float* h_b     = (float*)alloc((size_t)N * HDIM * 4);

  hipMemsetAsync(counts, 0, (size_t)N * 4, stream);
  count_kernel<<<(E + 255) / 256, 256, 0, stream>>>(dstp, counts, E);
  dinv_kernel<<<(N + 255) / 256, 256, 0, stream>>>(counts, dinvp, N);
  scan_kernel<<<1, 1024, 0, stream>>>(counts, rowptr, cursor, N);
  fill_kernel<<<(E + 255) / 256, 256, 0, stream>>>(srcp, dstp, cursor, dinvp, csr_src, csr_w, E);

  layer1_kernel<<<N, 64, 0, stream>>>(x, W1, b1, g1, be1, rowptr, csr_src, csr_w, dinvp, h_a, N);
  int nb = (N + ROWS - 1) / ROWS;
  layer_kernel<<<nb, 256, 0, stream>>>(h_a, W2, b2, g2, be2, rowptr, csr_src, csr_w, dinvp, h_b,
                                       rW1, rb1, rW2, rb2, out, N, 1);
  layer_kernel<<<nb, 256, 0, stream>>>(h_b, W3, b3, g3, be3, rowptr, csr_src, csr_w, dinvp, h_a,
                                       rW1, rb1, rW2, rb2, out, N, 2);
}

// Round 3
// 529.837 us; speedup vs baseline: 1.4626x; 1.2390x over previous
//
#include <hip/hip_runtime.h>
#include <hip/hip_fp16.h>
#include <math.h>

#define HDIM 128
#define ROWS 16
#define LN_EPS 1e-5f

// ---------------- CSR build (rows padded to multiples of 8, pad entries w=0,s=0) ----------------

__global__ void count_kernel(const int* __restrict__ dst, int* __restrict__ counts, int E) {
  int e = blockIdx.x * blockDim.x + threadIdx.x;
  if (e < E) atomicAdd(&counts[dst[e]], 1);
}

__global__ void dinv_kernel(const int* __restrict__ counts, float* __restrict__ dinv, int n) {
  int v = blockIdx.x * blockDim.x + threadIdx.x;
  if (v < n) dinv[v] = rsqrtf((float)(counts[v] + 1));  // +1 self-loop => deg >= 1
}

__global__ __launch_bounds__(1024) void scan_kernel(const int* __restrict__ counts,
                                                    int* __restrict__ rowptr,
                                                    int* __restrict__ cursor, int n) {
  __shared__ int sh[1024];
  int tid = threadIdx.x;
  int chunk = (n + 1023) >> 10;
  int start = tid * chunk;
  int end = start + chunk;
  if (end > n) end = n;
  int sum = 0;
  for (int i = start; i < end; ++i) sum += (counts[i] + 7) & ~7;  // padded degree
  sh[tid] = sum;
  __syncthreads();
  for (int off = 1; off < 1024; off <<= 1) {
    int v = (tid >= off) ? sh[tid - off] : 0;
    __syncthreads();
    sh[tid] += v;
    __syncthreads();
  }
  int prefix = (tid == 0) ? 0 : sh[tid - 1];
  for (int i = start; i < end; ++i) {
    rowptr[i] = prefix;
    cursor[i] = prefix;
    prefix += (counts[i] + 7) & ~7;
  }
  if (tid == 1023) rowptr[n] = sh[1023];
}

__global__ void fill_kernel(const int* __restrict__ src, const int* __restrict__ dst,
                            int* __restrict__ cursor, const float* __restrict__ dinv,
                            int* __restrict__ csr_src, float* __restrict__ csr_w, int E) {
  int e = blockIdx.x * blockDim.x + threadIdx.x;
  if (e < E) {
    int s = src[e], d = dst[e];
    int pos = atomicAdd(&cursor[d], 1);
    csr_src[pos] = s;
    csr_w[pos] = dinv[s] * dinv[d];
  }
}

// ---------------- Layer 1: one wave/node, 6-wide aggregate, 6->128 GEMM + LN + ReLU, fp16 out ----

__global__ __launch_bounds__(256) void layer1_kernel(
    const float* __restrict__ x, const float* __restrict__ W1,
    const float* __restrict__ b1, const float* __restrict__ gam,
    const float* __restrict__ bet, const int* __restrict__ rowptr,
    const int* __restrict__ csr_src, const float* __restrict__ csr_w,
    const float* __restrict__ dinv, __half* __restrict__ hout, int n) {
  int v = blockIdx.x * 4 + (threadIdx.x >> 6);
  if (v >= n) return;
  int lane = threadIdx.x & 63;
  float a[6] = {0.f, 0.f, 0.f, 0.f, 0.f, 0.f};
  int e1 = rowptr[v + 1];
  for (int e = rowptr[v] + lane; e < e1; e += 64) {
    int s = csr_src[e];
    float w = csr_w[e];  // pad entries have w=0
#pragma unroll
    for (int j = 0; j < 6; ++j) a[j] = fmaf(x[s * 6 + j], w, a[j]);
  }
  if (lane == 0) {
    float dv = dinv[v];
    float w = dv * dv;
#pragma unroll
    for (int j = 0; j < 6; ++j) a[j] = fmaf(x[v * 6 + j], w, a[j]);
  }
#pragma unroll
  for (int off = 32; off >= 1; off >>= 1) {
#pragma unroll
    for (int j = 0; j < 6; ++j) a[j] += __shfl_xor(a[j], off, 64);
  }
  int f0 = lane, f1 = lane + 64;
  float o0 = b1[f0], o1 = b1[f1];
#pragma unroll
  for (int j = 0; j < 6; ++j) {
    o0 = fmaf(a[j], W1[j * HDIM + f0], o0);
    o1 = fmaf(a[j], W1[j * HDIM + f1], o1);
  }
  float s = o0 + o1, q = o0 * o0 + o1 * o1;
#pragma unroll
  for (int off = 32; off >= 1; off >>= 1) {
    s += __shfl_xor(s, off, 64);
    q += __shfl_xor(q, off, 64);
  }
  float m = s * (1.0f / HDIM);
  float var = fmaxf(q * (1.0f / HDIM) - m * m, 0.f);
  float rs = rsqrtf(var + LN_EPS);
  float y0 = fmaxf(fmaf((o0 - m) * rs, gam[f0], bet[f0]), 0.f);
  float y1 = fmaxf(fmaf((o1 - m) * rs, gam[f1], bet[f1]), 0.f);
  hout[v * HDIM + f0] = __float2half(y0);
  hout[v * HDIM + f1] = __float2half(y1);
}

// ---------------- Aggregation: one wave/node, 8 outstanding half2 row-gathers ----------------

__global__ __launch_bounds__(256) void agg_kernel(
    const __half* __restrict__ hin, const int* __restrict__ rowptr,
    const int* __restrict__ csr_src, const float* __restrict__ csr_w,
    const float* __restrict__ dinv, float* __restrict__ agg, int n) {
  int v = blockIdx.x * 4 + (threadIdx.x >> 6);
  if (v >= n) return;
  int lane = threadIdx.x & 63;
  const __half2* h2 = (const __half2*)hin;
  float dv = dinv[v];
  float sw = dv * dv;
  float2 hf = __half22float2(h2[v * 64 + lane]);
  float ax = hf.x * sw, ay = hf.y * sw;  // self-loop
  int e = rowptr[v], e1 = rowptr[v + 1];  // padded: (e1-e) % 8 == 0
  for (; e < e1; e += 8) {
    int s[8];
    float w[8];
#pragma unroll
    for (int u = 0; u < 8; ++u) {
      s[u] = csr_src[e + u];
      w[u] = csr_w[e + u];
    }
    __half2 g[8];
#pragma unroll
    for (int u = 0; u < 8; ++u) g[u] = h2[s[u] * 64 + lane];
#pragma unroll
    for (int u = 0; u < 8; ++u) {
      float2 f = __half22float2(g[u]);
      ax = fmaf(f.x, w[u], ax);
      ay = fmaf(f.y, w[u], ay);
    }
  }
  float2 r;
  r.x = ax;
  r.y = ay;
  ((float2*)agg)[v * 64 + lane] = r;
}

// ---------------- GEMM + LN (+ReLU -> fp16 h | +head -> out) ----------------

#define FMA4(A, S, Wv)            \
  A.x = fmaf(S, Wv.x, A.x);       \
  A.y = fmaf(S, Wv.y, A.y);       \
  A.z = fmaf(S, Wv.z, A.z);       \
  A.w = fmaf(S, Wv.w, A.w);

// mode: 1 = LN+ReLU -> hout(fp16). 2 = LN + fused regressor head -> out(fp32).
__global__ __launch_bounds__(256) void gemm_kernel(
    const float* __restrict__ agg, const float* __restrict__ W,
    const float* __restrict__ bias, const float* __restrict__ gam,
    const float* __restrict__ bet, __half* __restrict__ hout,
    const float* __restrict__ rW1, const float* __restrict__ rb1,
    const float* __restrict__ rW2, const float* __restrict__ rb2,
    float* __restrict__ out, int n, int mode) {
  __shared__ float s_a[ROWS][HDIM];  // 8 KB
  int tid = threadIdx.x;
  int v0 = blockIdx.x * ROWS;

  // Stage agg tile: 16 rows x 128 = 512 float4, 2 per thread, coalesced.
  {
    const float4* a4 = (const float4*)agg;
    float4* s4 = (float4*)s_a;
#pragma unroll
    for (int j = 0; j < 2; ++j) {
      int fi = tid + j * 256;
      int row = fi >> 5;  // 32 float4 per row
      int v = v0 + row;
      float4 val = make_float4(0.f, 0.f, 0.f, 0.f);
      if (v < n) val = a4[v * 32 + (fi & 31)];
      s4[fi] = val;
    }
  }
  __syncthreads();

  // GEMM: 2 rows x 4 cols per thread.
  int colg = tid & 31;
  int rowg = tid >> 5;
  int f4 = colg << 2;
  int r0 = rowg << 1, r1 = r0 + 1;
  float4 bv = *(const float4*)&bias[f4];
  float4 acc0 = bv, acc1 = bv;
  const float4* a0p = (const float4*)s_a[r0];
  const float4* a1p = (const float4*)s_a[r1];
#pragma unroll 8
  for (int kc = 0; kc < HDIM / 4; ++kc) {
    float4 a0 = a0p[kc];
    float4 a1 = a1p[kc];
    const float* wp = &W[(kc << 2) * HDIM + f4];
    float4 w0 = *(const float4*)wp;
    float4 w1 = *(const float4*)(wp + HDIM);
    float4 w2 = *(const float4*)(wp + 2 * HDIM);
    float4 w3 = *(const float4*)(wp + 3 * HDIM);
    FMA4(acc0, a0.x, w0) FMA4(acc0, a0.y, w1) FMA4(acc0, a0.z, w2) FMA4(acc0, a0.w, w3)
    FMA4(acc1, a1.x, w0) FMA4(acc1, a1.y, w1) FMA4(acc1, a1.z, w2) FMA4(acc1, a1.w, w3)
  }

  // LayerNorm via width-32 butterflies (each row owned by one 32-lane segment).
  float s0 = acc0.x + acc0.y + acc0.z + acc0.w;
  float q0 = acc0.x * acc0.x + acc0.y * acc0.y + acc0.z * acc0.z + acc0.w * acc0.w;
  float s1 = acc1.x + acc1.y + acc1.z + acc1.w;
  float q1 = acc1.x * acc1.x + acc1.y * acc1.y + acc1.z * acc1.z + acc1.w * acc1.w;
#pragma unroll
  for (int off = 16; off >= 1; off >>= 1) {
    s0 += __shfl_xor(s0, off, 32);
    q0 += __shfl_xor(q0, off, 32);
    s1 += __shfl_xor(s1, off, 32);
    q1 += __shfl_xor(q1, off, 32);
  }
  float inv = 1.0f / HDIM;
  float m0 = s0 * inv, m1 = s1 * inv;
  float rs0 = rsqrtf(fmaxf(q0 * inv - m0 * m0, 0.f) + LN_EPS);
  float rs1 = rsqrtf(fmaxf(q1 * inv - m1 * m1, 0.f) + LN_EPS);
  float4 gv = *(const float4*)&gam[f4];
  float4 bev = *(const float4*)&bet[f4];
  float4 y0, y1;
  y0.x = fmaf((acc0.x - m0) * rs0, gv.x, bev.x);
  y0.y = fmaf((acc0.y - m0) * rs0, gv.y, bev.y);
  y0.z = fmaf((acc0.z - m0) * rs0, gv.z, bev.z);
  y0.w = fmaf((acc0.w - m0) * rs0, gv.w, bev.w);
  y1.x = fmaf((acc1.x - m1) * rs1, gv.x, bev.x);
  y1.y = fmaf((acc1.y - m1) * rs1, gv.y, bev.y);
  y1.z = fmaf((acc1.z - m1) * rs1, gv.z, bev.z);
  y1.w = fmaf((acc1.w - m1) * rs1, gv.w, bev.w);

  if (mode == 1) {
    y0.x = fmaxf(y0.x, 0.f); y0.y = fmaxf(y0.y, 0.f);
    y0.z = fmaxf(y0.z, 0.f); y0.w = fmaxf(y0.w, 0.f);
    y1.x = fmaxf(y1.x, 0.f); y1.y = fmaxf(y1.y, 0.f);
    y1.z = fmaxf(y1.z, 0.f); y1.w = fmaxf(y1.w, 0.f);
    if (v0 + r0 < n) {
      __half2* hp = (__half2*)&hout[(v0 + r0) * HDIM + f4];
      hp[0] = __floats2half2_rn(y0.x, y0.y);
      hp[1] = __floats2half2_rn(y0.z, y0.w);
    }
    if (v0 + r1 < n) {
      __half2* hp = (__half2*)&hout[(v0 + r1) * HDIM + f4];
      hp[0] = __floats2half2_rn(y1.x, y1.y);
      hp[1] = __floats2half2_rn(y1.z, y1.w);
    }
    return;
  }

  // mode 2: fused regressor head. Round-trip y through s_a (reuse).
  __syncthreads();
  *(float4*)&s_a[r0][f4] = y0;
  *(float4*)&s_a[r1][f4] = y1;
  __syncthreads();

  int r = tid >> 4;  // 0..15
  int t = tid & 15;  // 0..15
  int j4 = t << 2;
  float4 hacc = *(const float4*)&rb1[j4];
#pragma unroll 8
  for (int kk = 0; kk < HDIM / 4; ++kk) {
    int kc = (kk + r) & (HDIM / 4 - 1);  // rotate start per row: break LDS aliasing
    float4 av = ((const float4*)s_a[r])[kc];
    int kbase = kc << 2;
    float4 w0 = *(const float4*)&rW1[(kbase + 0) * 64 + j4];
    float4 w1 = *(const float4*)&rW1[(kbase + 1) * 64 + j4];
    float4 w2 = *(const float4*)&rW1[(kbase + 2) * 64 + j4];
    float4 w3 = *(const float4*)&rW1[(kbase + 3) * 64 + j4];
    FMA4(hacc, av.x, w0) FMA4(hacc, av.y, w1) FMA4(hacc, av.z, w2) FMA4(hacc, av.w, w3)
  }
  hacc.x = fmaxf(hacc.x, 0.f);
  hacc.y = fmaxf(hacc.y, 0.f);
  hacc.z = fmaxf(hacc.z, 0.f);
  hacc.w = fmaxf(hacc.w, 0.f);
  float4 w2v = *(const float4*)&rW2[j4];
  float p = hacc.x * w2v.x + hacc.y * w2v.y + hacc.z * w2v.z + hacc.w * w2v.w;
#pragma unroll
  for (int off = 8; off >= 1; off >>= 1) p += __shfl_xor(p, off, 16);
  int v = v0 + r;
  if (t == 0 && v < n) out[v] = 1.0f / (1.0f + expf(-(p + rb2[0])));
}

// ---------------- Launch ----------------

extern "C" void kernel_launch(void* const* d_in, const int* in_sizes, int n_in,
                              void* d_out, int out_size, void* d_ws, size_t ws_size,
                              hipStream_t stream) {
  const float* x   = (const float*)d_in[0];
  const int*  eidx = (const int*)d_in[1];
  const float* W1  = (const float*)d_in[2];
  const float* b1  = (const float*)d_in[3];
  const float* W2  = (const float*)d_in[4];
  const float* b2  = (const float*)d_in[5];
  const float* W3  = (const float*)d_in[6];
  const float* b3  = (const float*)d_in[7];
  const float* g1  = (const float*)d_in[8];
  const float* be1 = (const float*)d_in[9];
  const float* g2  = (const float*)d_in[10];
  const float* be2 = (const float*)d_in[11];
  const float* g3  = (const float*)d_in[12];
  const float* be3 = (const float*)d_in[13];
  const float* rW1 = (const float*)d_in[14];
  const float* rb1 = (const float*)d_in[15];
  const float* rW2 = (const float*)d_in[16];
  const float* rb2 = (const float*)d_in[17];

  int N = in_sizes[0] / 6;
  int E = in_sizes[1] / 2;
  int Epad = E + 8 * N;  // upper bound on padded CSR size
  const int* srcp = eidx;
  const int* dstp = eidx + E;
  float* out = (float*)d_out;

  char* p = (char*)d_ws;
  auto alloc = [&](size_t bytes) -> void* {
    void* r = (void*)p;
    p += (bytes + 255) & ~(size_t)255;
    return r;
  };
  int*    counts  = (int*)alloc((size_t)N * 4);
  int*    rowptr  = (int*)alloc((size_t)(N + 1) * 4);
  int*    cursor  = (int*)alloc((size_t)N * 4);
  float*  dinvp   = (float*)alloc((size_t)N * 4);
  int*    csr_src = (int*)alloc((size_t)Epad * 4);
  float*  csr_w   = (float*)alloc((size_t)Epad * 4);
  __half* h16_a   = (__half*)alloc((size_t)N * HDIM * 2);
  __half* h16_b   = (__half*)alloc((size_t)N * HDIM * 2);
  float*  aggbuf  = (float*)alloc((size_t)N * HDIM * 4);

  hipMemsetAsync(counts, 0, (size_t)N * 4, stream);
  hipMemsetAsync(csr_src, 0, (size_t)Epad * 4, stream);  // pads gather row 0
  hipMemsetAsync(csr_w, 0, (size_t)Epad * 4, stream);    // pads weight 0
  count_kernel<<<(E + 255) / 256, 256, 0, stream>>>(dstp, counts, E);
  dinv_kernel<<<(N + 255) / 256, 256, 0, stream>>>(counts, dinvp, N);
  scan_kernel<<<1, 1024, 0, stream>>>(counts, rowptr, cursor, N);
  fill_kernel<<<(E + 255) / 256, 256, 0, stream>>>(srcp, dstp, cursor, dinvp, csr_src, csr_w, E);

  int nw = (N + 3) / 4;        // blocks of 4 waves, one wave per node
  int nb = (N + ROWS - 1) / ROWS;
  layer1_kernel<<<nw, 256, 0, stream>>>(x, W1, b1, g1, be1, rowptr, csr_src, csr_w, dinvp, h16_a, N);
  agg_kernel<<<nw, 256, 0, stream>>>(h16_a, rowptr, csr_src, csr_w, dinvp, aggbuf, N);
  gemm_kernel<<<nb, 256, 0, stream>>>(aggbuf, W2, b2, g2, be2, h16_b,
                                      rW1, rb1, rW2, rb2, out, N, 1);
  agg_kernel<<<nw, 256, 0, stream>>>(h16_b, rowptr, csr_src, csr_w, dinvp, aggbuf, N);
  gemm_kernel<<<nb, 256, 0, stream>>>(aggbuf, W3, b3, g3, be3, h16_b,
                                      rW1, rb1, rW2, rb2, out, N, 2);
}

// Round 4
// 429.058 us; speedup vs baseline: 1.8062x; 1.2349x over previous
//
#include <hip/hip_runtime.h>
#include <hip/hip_fp16.h>
#include <math.h>

#define HDIM 128
#define ROWS 16
#define LN_EPS 1e-5f
#define SCAN_CHUNK 1024  // elements per scan block (256 threads x 4)

// ---------------- CSR build (rows padded to multiples of 8, pad entries w=0,s=0) ----------------

__global__ void count_kernel(const int* __restrict__ dst, int* __restrict__ counts, int E) {
  int e = blockIdx.x * blockDim.x + threadIdx.x;
  if (e < E) atomicAdd(&counts[dst[e]], 1);
}

__global__ void dinv_kernel(const int* __restrict__ counts, float* __restrict__ dinv, int n) {
  int v = blockIdx.x * blockDim.x + threadIdx.x;
  if (v < n) dinv[v] = rsqrtf((float)(counts[v] + 1));  // +1 self-loop => deg >= 1
}

// Hierarchical scan of padded degrees: scan1 (block sums) -> scan2 (scan sums) -> scan3 (emit).
__global__ __launch_bounds__(256) void scan1_kernel(const int* __restrict__ counts,
                                                    int* __restrict__ blocksum, int n) {
  int base = blockIdx.x * SCAN_CHUNK;
  int tid = threadIdx.x;
  int sum = 0;
#pragma unroll
  for (int j = 0; j < 4; ++j) {
    int i = base + tid * 4 + j;
    if (i < n) sum += (counts[i] + 7) & ~7;
  }
#pragma unroll
  for (int off = 32; off >= 1; off >>= 1) sum += __shfl_xor(sum, off, 64);
  __shared__ int wsum[4];
  if ((tid & 63) == 0) wsum[tid >> 6] = sum;
  __syncthreads();
  if (tid == 0) blocksum[blockIdx.x] = wsum[0] + wsum[1] + wsum[2] + wsum[3];
}

__global__ __launch_bounds__(256) void scan2_kernel(int* __restrict__ blocksum, int nblk) {
  __shared__ int sh[256];
  int tid = threadIdx.x;
  sh[tid] = (tid < nblk) ? blocksum[tid] : 0;
  __syncthreads();
  for (int off = 1; off < 256; off <<= 1) {
    int t = (tid >= off) ? sh[tid - off] : 0;
    __syncthreads();
    sh[tid] += t;
    __syncthreads();
  }
  if (tid < nblk) blocksum[tid] = sh[tid];  // inclusive scan
}

__global__ __launch_bounds__(256) void scan3_kernel(const int* __restrict__ counts,
                                                    const int* __restrict__ blocksum,
                                                    int* __restrict__ rowptr,
                                                    int* __restrict__ cursor, int n, int nblk) {
  int base = blockIdx.x * SCAN_CHUNK;
  int tid = threadIdx.x;
  int c[4];
  int s = 0;
#pragma unroll
  for (int j = 0; j < 4; ++j) {
    int i = base + tid * 4 + j;
    c[j] = (i < n) ? ((counts[i] + 7) & ~7) : 0;
    s += c[j];
  }
  // exclusive scan of per-thread sums across the 256-thread block
  int lane = tid & 63, wid = tid >> 6;
  int incl = s;
#pragma unroll
  for (int off = 1; off < 64; off <<= 1) {
    int t = __shfl_up(incl, off, 64);
    if (lane >= off) incl += t;
  }
  __shared__ int wsum[4];
  if (lane == 63) wsum[wid] = incl;
  __syncthreads();
  int woff = 0;
  for (int w = 0; w < wid; ++w) woff += wsum[w];
  int p = (blockIdx.x == 0 ? 0 : blocksum[blockIdx.x - 1]) + woff + (incl - s);
#pragma unroll
  for (int j = 0; j < 4; ++j) {
    int i = base + tid * 4 + j;
    if (i < n) {
      rowptr[i] = p;
      cursor[i] = p;
    }
    p += c[j];
  }
  if (blockIdx.x == nblk - 1 && tid == 255) rowptr[n] = blocksum[nblk - 1];
}

__global__ void fill_kernel(const int* __restrict__ src, const int* __restrict__ dst,
                            int* __restrict__ cursor, const float* __restrict__ dinv,
                            int* __restrict__ csr_src, float* __restrict__ csr_w, int E) {
  int e = blockIdx.x * blockDim.x + threadIdx.x;
  if (e < E) {
    int s = src[e], d = dst[e];
    int pos = atomicAdd(&cursor[d], 1);
    csr_src[pos] = s;
    csr_w[pos] = dinv[s] * dinv[d];
  }
}

// ---------------- Layer 1: one wave/node, 6-wide aggregate, 6->128 GEMM + LN + ReLU, fp16 out ----

__global__ __launch_bounds__(256) void layer1_kernel(
    const float* __restrict__ x, const float* __restrict__ W1,
    const float* __restrict__ b1, const float* __restrict__ gam,
    const float* __restrict__ bet, const int* __restrict__ rowptr,
    const int* __restrict__ csr_src, const float* __restrict__ csr_w,
    const float* __restrict__ dinv, __half* __restrict__ hout, int n) {
  int v = blockIdx.x * 4 + (threadIdx.x >> 6);
  if (v >= n) return;
  int lane = threadIdx.x & 63;
  float a[6] = {0.f, 0.f, 0.f, 0.f, 0.f, 0.f};
  int e1 = rowptr[v + 1];
  for (int e = rowptr[v] + lane; e < e1; e += 64) {
    int s = csr_src[e];
    float w = csr_w[e];  // pad entries have w=0
#pragma unroll
    for (int j = 0; j < 6; ++j) a[j] = fmaf(x[s * 6 + j], w, a[j]);
  }
  if (lane == 0) {
    float dv = dinv[v];
    float w = dv * dv;
#pragma unroll
    for (int j = 0; j < 6; ++j) a[j] = fmaf(x[v * 6 + j], w, a[j]);
  }
#pragma unroll
  for (int off = 32; off >= 1; off >>= 1) {
#pragma unroll
    for (int j = 0; j < 6; ++j) a[j] += __shfl_xor(a[j], off, 64);
  }
  int f0 = lane, f1 = lane + 64;
  float o0 = b1[f0], o1 = b1[f1];
#pragma unroll
  for (int j = 0; j < 6; ++j) {
    o0 = fmaf(a[j], W1[j * HDIM + f0], o0);
    o1 = fmaf(a[j], W1[j * HDIM + f1], o1);
  }
  float s = o0 + o1, q = o0 * o0 + o1 * o1;
#pragma unroll
  for (int off = 32; off >= 1; off >>= 1) {
    s += __shfl_xor(s, off, 64);
    q += __shfl_xor(q, off, 64);
  }
  float m = s * (1.0f / HDIM);
  float var = fmaxf(q * (1.0f / HDIM) - m * m, 0.f);
  float rs = rsqrtf(var + LN_EPS);
  float y0 = fmaxf(fmaf((o0 - m) * rs, gam[f0], bet[f0]), 0.f);
  float y1 = fmaxf(fmaf((o1 - m) * rs, gam[f1], bet[f1]), 0.f);
  hout[v * HDIM + f0] = __float2half(y0);
  hout[v * HDIM + f1] = __float2half(y1);
}

// ---------------- Aggregation: one wave/node, 8 outstanding half2 row-gathers ----------------

__global__ __launch_bounds__(256) void agg_kernel(
    const __half* __restrict__ hin, const int* __restrict__ rowptr,
    const int* __restrict__ csr_src, const float* __restrict__ csr_w,
    const float* __restrict__ dinv, float* __restrict__ agg, int n) {
  int v = blockIdx.x * 4 + (threadIdx.x >> 6);
  if (v >= n) return;
  int lane = threadIdx.x & 63;
  const __half2* h2 = (const __half2*)hin;
  float dv = dinv[v];
  float sw = dv * dv;
  float2 hf = __half22float2(h2[v * 64 + lane]);
  float ax = hf.x * sw, ay = hf.y * sw;  // self-loop
  int e = rowptr[v], e1 = rowptr[v + 1];  // padded: (e1-e) % 8 == 0
  for (; e < e1; e += 8) {
    int s[8];
    float w[8];
#pragma unroll
    for (int u = 0; u < 8; ++u) {
      s[u] = csr_src[e + u];
      w[u] = csr_w[e + u];
    }
    __half2 g[8];
#pragma unroll
    for (int u = 0; u < 8; ++u) g[u] = h2[s[u] * 64 + lane];
#pragma unroll
    for (int u = 0; u < 8; ++u) {
      float2 f = __half22float2(g[u]);
      ax = fmaf(f.x, w[u], ax);
      ay = fmaf(f.y, w[u], ay);
    }
  }
  float2 r;
  r.x = ax;
  r.y = ay;
  ((float2*)agg)[v * 64 + lane] = r;
}

// ---------------- GEMM + LN (+ReLU -> fp16 h | +head -> out) ----------------

#define FMA4(A, S, Wv)            \
  A.x = fmaf(S, Wv.x, A.x);       \
  A.y = fmaf(S, Wv.y, A.y);       \
  A.z = fmaf(S, Wv.z, A.z);       \
  A.w = fmaf(S, Wv.w, A.w);

// mode: 1 = LN+ReLU -> hout(fp16). 2 = LN + fused regressor head -> out(fp32).
__global__ __launch_bounds__(256) void gemm_kernel(
    const float* __restrict__ agg, const float* __restrict__ W,
    const float* __restrict__ bias, const float* __restrict__ gam,
    const float* __restrict__ bet, __half* __restrict__ hout,
    const float* __restrict__ rW1, const float* __restrict__ rb1,
    const float* __restrict__ rW2, const float* __restrict__ rb2,
    float* __restrict__ out, int n, int mode) {
  __shared__ float s_a[ROWS][HDIM];  // 8 KB
  int tid = threadIdx.x;
  int v0 = blockIdx.x * ROWS;

  // Stage agg tile: 16 rows x 128 = 512 float4, 2 per thread, coalesced.
  {
    const float4* a4 = (const float4*)agg;
    float4* s4 = (float4*)s_a;
#pragma unroll
    for (int j = 0; j < 2; ++j) {
      int fi = tid + j * 256;
      int row = fi >> 5;  // 32 float4 per row
      int v = v0 + row;
      float4 val = make_float4(0.f, 0.f, 0.f, 0.f);
      if (v < n) val = a4[v * 32 + (fi & 31)];
      s4[fi] = val;
    }
  }
  __syncthreads();

  // GEMM: 2 rows x 4 cols per thread.
  int colg = tid & 31;
  int rowg = tid >> 5;
  int f4 = colg << 2;
  int r0 = rowg << 1, r1 = r0 + 1;
  float4 bv = *(const float4*)&bias[f4];
  float4 acc0 = bv, acc1 = bv;
  const float4* a0p = (const float4*)s_a[r0];
  const float4* a1p = (const float4*)s_a[r1];
#pragma unroll 8
  for (int kc = 0; kc < HDIM / 4; ++kc) {
    float4 a0 = a0p[kc];
    float4 a1 = a1p[kc];
    const float* wp = &W[(kc << 2) * HDIM + f4];
    float4 w0 = *(const float4*)wp;
    float4 w1 = *(const float4*)(wp + HDIM);
    float4 w2 = *(const float4*)(wp + 2 * HDIM);
    float4 w3 = *(const float4*)(wp + 3 * HDIM);
    FMA4(acc0, a0.x, w0) FMA4(acc0, a0.y, w1) FMA4(acc0, a0.z, w2) FMA4(acc0, a0.w, w3)
    FMA4(acc1, a1.x, w0) FMA4(acc1, a1.y, w1) FMA4(acc1, a1.z, w2) FMA4(acc1, a1.w, w3)
  }

  // LayerNorm via width-32 butterflies (each row owned by one 32-lane segment).
  float s0 = acc0.x + acc0.y + acc0.z + acc0.w;
  float q0 = acc0.x * acc0.x + acc0.y * acc0.y + acc0.z * acc0.z + acc0.w * acc0.w;
  float s1 = acc1.x + acc1.y + acc1.z + acc1.w;
  float q1 = acc1.x * acc1.x + acc1.y * acc1.y + acc1.z * acc1.z + acc1.w * acc1.w;
#pragma unroll
  for (int off = 16; off >= 1; off >>= 1) {
    s0 += __shfl_xor(s0, off, 32);
    q0 += __shfl_xor(q0, off, 32);
    s1 += __shfl_xor(s1, off, 32);
    q1 += __shfl_xor(q1, off, 32);
  }
  float inv = 1.0f / HDIM;
  float m0 = s0 * inv, m1 = s1 * inv;
  float rs0 = rsqrtf(fmaxf(q0 * inv - m0 * m0, 0.f) + LN_EPS);
  float rs1 = rsqrtf(fmaxf(q1 * inv - m1 * m1, 0.f) + LN_EPS);
  float4 gv = *(const float4*)&gam[f4];
  float4 bev = *(const float4*)&bet[f4];
  float4 y0, y1;
  y0.x = fmaf((acc0.x - m0) * rs0, gv.x, bev.x);
  y0.y = fmaf((acc0.y - m0) * rs0, gv.y, bev.y);
  y0.z = fmaf((acc0.z - m0) * rs0, gv.z, bev.z);
  y0.w = fmaf((acc0.w - m0) * rs0, gv.w, bev.w);
  y1.x = fmaf((acc1.x - m1) * rs1, gv.x, bev.x);
  y1.y = fmaf((acc1.y - m1) * rs1, gv.y, bev.y);
  y1.z = fmaf((acc1.z - m1) * rs1, gv.z, bev.z);
  y1.w = fmaf((acc1.w - m1) * rs1, gv.w, bev.w);

  if (mode == 1) {
    y0.x = fmaxf(y0.x, 0.f); y0.y = fmaxf(y0.y, 0.f);
    y0.z = fmaxf(y0.z, 0.f); y0.w = fmaxf(y0.w, 0.f);
    y1.x = fmaxf(y1.x, 0.f); y1.y = fmaxf(y1.y, 0.f);
    y1.z = fmaxf(y1.z, 0.f); y1.w = fmaxf(y1.w, 0.f);
    if (v0 + r0 < n) {
      __half2* hp = (__half2*)&hout[(v0 + r0) * HDIM + f4];
      hp[0] = __floats2half2_rn(y0.x, y0.y);
      hp[1] = __floats2half2_rn(y0.z, y0.w);
    }
    if (v0 + r1 < n) {
      __half2* hp = (__half2*)&hout[(v0 + r1) * HDIM + f4];
      hp[0] = __floats2half2_rn(y1.x, y1.y);
      hp[1] = __floats2half2_rn(y1.z, y1.w);
    }
    return;
  }

  // mode 2: fused regressor head. Round-trip y through s_a (reuse).
  __syncthreads();
  *(float4*)&s_a[r0][f4] = y0;
  *(float4*)&s_a[r1][f4] = y1;
  __syncthreads();

  int r = tid >> 4;  // 0..15
  int t = tid & 15;  // 0..15
  int j4 = t << 2;
  float4 hacc = *(const float4*)&rb1[j4];
#pragma unroll 8
  for (int kk = 0; kk < HDIM / 4; ++kk) {
    int kc = (kk + r) & (HDIM / 4 - 1);  // rotate start per row: break LDS aliasing
    float4 av = ((const float4*)s_a[r])[kc];
    int kbase = kc << 2;
    float4 w0 = *(const float4*)&rW1[(kbase + 0) * 64 + j4];
    float4 w1 = *(const float4*)&rW1[(kbase + 1) * 64 + j4];
    float4 w2 = *(const float4*)&rW1[(kbase + 2) * 64 + j4];
    float4 w3 = *(const float4*)&rW1[(kbase + 3) * 64 + j4];
    FMA4(hacc, av.x, w0) FMA4(hacc, av.y, w1) FMA4(hacc, av.z, w2) FMA4(hacc, av.w, w3)
  }
  hacc.x = fmaxf(hacc.x, 0.f);
  hacc.y = fmaxf(hacc.y, 0.f);
  hacc.z = fmaxf(hacc.z, 0.f);
  hacc.w = fmaxf(hacc.w, 0.f);
  float4 w2v = *(const float4*)&rW2[j4];
  float p = hacc.x * w2v.x + hacc.y * w2v.y + hacc.z * w2v.z + hacc.w * w2v.w;
#pragma unroll
  for (int off = 8; off >= 1; off >>= 1) p += __shfl_xor(p, off, 16);
  int v = v0 + r;
  if (t == 0 && v < n) out[v] = 1.0f / (1.0f + expf(-(p + rb2[0])));
}

// ---------------- Launch ----------------

extern "C" void kernel_launch(void* const* d_in, const int* in_sizes, int n_in,
                              void* d_out, int out_size, void* d_ws, size_t ws_size,
                              hipStream_t stream) {
  const float* x   = (const float*)d_in[0];
  const int*  eidx = (const int*)d_in[1];
  const float* W1  = (const float*)d_in[2];
  const float* b1  = (const float*)d_in[3];
  const float* W2  = (const float*)d_in[4];
  const float* b2  = (const float*)d_in[5];
  const float* W3  = (const float*)d_in[6];
  const float* b3  = (const float*)d_in[7];
  const float* g1  = (const float*)d_in[8];
  const float* be1 = (const float*)d_in[9];
  const float* g2  = (const float*)d_in[10];
  const float* be2 = (const float*)d_in[11];
  const float* g3  = (const float*)d_in[12];
  const float* be3 = (const float*)d_in[13];
  const float* rW1 = (const float*)d_in[14];
  const float* rb1 = (const float*)d_in[15];
  const float* rW2 = (const float*)d_in[16];
  const float* rb2 = (const float*)d_in[17];

  int N = in_sizes[0] / 6;
  int E = in_sizes[1] / 2;
  int Epad = E + 8 * N;  // upper bound on padded CSR size
  const int* srcp = eidx;
  const int* dstp = eidx + E;
  float* out = (float*)d_out;

  char* p = (char*)d_ws;
  auto alloc = [&](size_t bytes) -> void* {
    void* r = (void*)p;
    p += (bytes + 255) & ~(size_t)255;
    return r;
  };
  int*    counts   = (int*)alloc((size_t)N * 4);
  int*    rowptr   = (int*)alloc((size_t)(N + 1) * 4);
  int*    cursor   = (int*)alloc((size_t)N * 4);
  float*  dinvp    = (float*)alloc((size_t)N * 4);
  int*    blocksum = (int*)alloc((size_t)1024 * 4);
  int*    csr_src  = (int*)alloc((size_t)Epad * 4);
  float*  csr_w    = (float*)alloc((size_t)Epad * 4);
  __half* h16_a    = (__half*)alloc((size_t)N * HDIM * 2);
  __half* h16_b    = (__half*)alloc((size_t)N * HDIM * 2);
  float*  aggbuf   = (float*)alloc((size_t)N * HDIM * 4);

  int nscan = (N + SCAN_CHUNK - 1) / SCAN_CHUNK;  // 49 for N=50000 (<=256 supported)

  hipMemsetAsync(counts, 0, (size_t)N * 4, stream);
  hipMemsetAsync(csr_src, 0, (size_t)Epad * 4, stream);  // pads gather row 0
  hipMemsetAsync(csr_w, 0, (size_t)Epad * 4, stream);    // pads weight 0
  count_kernel<<<(E + 255) / 256, 256, 0, stream>>>(dstp, counts, E);
  dinv_kernel<<<(N + 255) / 256, 256, 0, stream>>>(counts, dinvp, N);
  scan1_kernel<<<nscan, 256, 0, stream>>>(counts, blocksum, N);
  scan2_kernel<<<1, 256, 0, stream>>>(blocksum, nscan);
  scan3_kernel<<<nscan, 256, 0, stream>>>(counts, blocksum, rowptr, cursor, N, nscan);
  fill_kernel<<<(E + 255) / 256, 256, 0, stream>>>(srcp, dstp, cursor, dinvp, csr_src, csr_w, E);

  int nw = (N + 3) / 4;        // blocks of 4 waves, one wave per node
  int nb = (N + ROWS - 1) / ROWS;
  layer1_kernel<<<nw, 256, 0, stream>>>(x, W1, b1, g1, be1, rowptr, csr_src, csr_w, dinvp, h16_a, N);
  agg_kernel<<<nw, 256, 0, stream>>>(h16_a, rowptr, csr_src, csr_w, dinvp, aggbuf, N);
  gemm_kernel<<<nb, 256, 0, stream>>>(aggbuf, W2, b2, g2, be2, h16_b,
                                      rW1, rb1, rW2, rb2, out, N, 1);
  agg_kernel<<<nw, 256, 0, stream>>>(h16_b, rowptr, csr_src, csr_w, dinvp, aggbuf, N);
  gemm_kernel<<<nb, 256, 0, stream>>>(aggbuf, W3, b3, g3, be3, h16_b,
                                      rW1, rb1, rW2, rb2, out, N, 2);
}

// Round 5
// 307.544 us; speedup vs baseline: 2.5198x; 1.3951x over previous
//
#include <hip/hip_runtime.h>
#include <hip/hip_fp16.h>
#include <math.h>

#define HDIM 128
#define LN_EPS 1e-5f
#define SCAN_CHUNK 1024  // elements per scan block (256 threads x 4)

typedef _Float16 half8 __attribute__((ext_vector_type(8)));
typedef float f32x4 __attribute__((ext_vector_type(4)));

// ---------------- CSR build (rows padded to multiples of 8, pad entries w=0,s=0) ----------------

__global__ void count_kernel(const int* __restrict__ dst, int* __restrict__ counts, int E) {
  int e = blockIdx.x * blockDim.x + threadIdx.x;
  if (e < E) atomicAdd(&counts[dst[e]], 1);
}

__global__ void dinv_kernel(const int* __restrict__ counts, float* __restrict__ dinv, int n) {
  int v = blockIdx.x * blockDim.x + threadIdx.x;
  if (v < n) dinv[v] = rsqrtf((float)(counts[v] + 1));  // +1 self-loop => deg >= 1
}

__global__ __launch_bounds__(256) void scan1_kernel(const int* __restrict__ counts,
                                                    int* __restrict__ blocksum, int n) {
  int base = blockIdx.x * SCAN_CHUNK;
  int tid = threadIdx.x;
  int sum = 0;
#pragma unroll
  for (int j = 0; j < 4; ++j) {
    int i = base + tid * 4 + j;
    if (i < n) sum += (counts[i] + 7) & ~7;
  }
#pragma unroll
  for (int off = 32; off >= 1; off >>= 1) sum += __shfl_xor(sum, off, 64);
  __shared__ int wsum[4];
  if ((tid & 63) == 0) wsum[tid >> 6] = sum;
  __syncthreads();
  if (tid == 0) blocksum[blockIdx.x] = wsum[0] + wsum[1] + wsum[2] + wsum[3];
}

__global__ __launch_bounds__(256) void scan2_kernel(int* __restrict__ blocksum, int nblk) {
  __shared__ int sh[256];
  int tid = threadIdx.x;
  sh[tid] = (tid < nblk) ? blocksum[tid] : 0;
  __syncthreads();
  for (int off = 1; off < 256; off <<= 1) {
    int t = (tid >= off) ? sh[tid - off] : 0;
    __syncthreads();
    sh[tid] += t;
    __syncthreads();
  }
  if (tid < nblk) blocksum[tid] = sh[tid];  // inclusive scan
}

__global__ __launch_bounds__(256) void scan3_kernel(const int* __restrict__ counts,
                                                    const int* __restrict__ blocksum,
                                                    int* __restrict__ rowptr,
                                                    int* __restrict__ cursor, int n, int nblk) {
  int base = blockIdx.x * SCAN_CHUNK;
  int tid = threadIdx.x;
  int c[4];
  int s = 0;
#pragma unroll
  for (int j = 0; j < 4; ++j) {
    int i = base + tid * 4 + j;
    c[j] = (i < n) ? ((counts[i] + 7) & ~7) : 0;
    s += c[j];
  }
  int lane = tid & 63, wid = tid >> 6;
  int incl = s;
#pragma unroll
  for (int off = 1; off < 64; off <<= 1) {
    int t = __shfl_up(incl, off, 64);
    if (lane >= off) incl += t;
  }
  __shared__ int wsum[4];
  if (lane == 63) wsum[wid] = incl;
  __syncthreads();
  int woff = 0;
  for (int w = 0; w < wid; ++w) woff += wsum[w];
  int p = (blockIdx.x == 0 ? 0 : blocksum[blockIdx.x - 1]) + woff + (incl - s);
#pragma unroll
  for (int j = 0; j < 4; ++j) {
    int i = base + tid * 4 + j;
    if (i < n) {
      rowptr[i] = p;
      cursor[i] = p;
    }
    p += c[j];
  }
  if (blockIdx.x == nblk - 1 && tid == 255) rowptr[n] = blocksum[nblk - 1];
}

__global__ void fill_kernel(const int* __restrict__ src, const int* __restrict__ dst,
                            int* __restrict__ cursor, const float* __restrict__ dinv,
                            int* __restrict__ csr_src, float* __restrict__ csr_w, int E) {
  int e = blockIdx.x * blockDim.x + threadIdx.x;
  if (e < E) {
    int s = src[e], d = dst[e];
    int pos = atomicAdd(&cursor[d], 1);
    csr_src[pos] = s;
    csr_w[pos] = dinv[s] * dinv[d];
  }
}

// ---------------- Weight prep: out (C x R fp16, n-major) = transpose(in (R x C fp32)) ----------

__global__ void transpose_h_kernel(const float* __restrict__ in, __half* __restrict__ out,
                                   int R, int C) {
  int idx = blockIdx.x * 256 + threadIdx.x;
  if (idx < R * C) {
    int nn = idx / R, k = idx % R;
    out[idx] = __float2half(in[k * C + nn]);
  }
}

// ---------------- Layer 1: one wave/node, 6-wide aggregate, 6->128 GEMM + LN + ReLU, fp16 out ----

__global__ __launch_bounds__(256) void layer1_kernel(
    const float* __restrict__ x, const float* __restrict__ W1,
    const float* __restrict__ b1, const float* __restrict__ gam,
    const float* __restrict__ bet, const int* __restrict__ rowptr,
    const int* __restrict__ csr_src, const float* __restrict__ csr_w,
    const float* __restrict__ dinv, __half* __restrict__ hout, int n) {
  int v = blockIdx.x * 4 + (threadIdx.x >> 6);
  if (v >= n) return;
  int lane = threadIdx.x & 63;
  float a[6] = {0.f, 0.f, 0.f, 0.f, 0.f, 0.f};
  int e1 = rowptr[v + 1];
  for (int e = rowptr[v] + lane; e < e1; e += 64) {
    int s = csr_src[e];
    float w = csr_w[e];  // pad entries have w=0
#pragma unroll
    for (int j = 0; j < 6; ++j) a[j] = fmaf(x[s * 6 + j], w, a[j]);
  }
  if (lane == 0) {
    float dv = dinv[v];
    float w = dv * dv;
#pragma unroll
    for (int j = 0; j < 6; ++j) a[j] = fmaf(x[v * 6 + j], w, a[j]);
  }
#pragma unroll
  for (int off = 32; off >= 1; off >>= 1) {
#pragma unroll
    for (int j = 0; j < 6; ++j) a[j] += __shfl_xor(a[j], off, 64);
  }
  int f0 = lane, f1 = lane + 64;
  float o0 = b1[f0], o1 = b1[f1];
#pragma unroll
  for (int j = 0; j < 6; ++j) {
    o0 = fmaf(a[j], W1[j * HDIM + f0], o0);
    o1 = fmaf(a[j], W1[j * HDIM + f1], o1);
  }
  float s = o0 + o1, q = o0 * o0 + o1 * o1;
#pragma unroll
  for (int off = 32; off >= 1; off >>= 1) {
    s += __shfl_xor(s, off, 64);
    q += __shfl_xor(q, off, 64);
  }
  float m = s * (1.0f / HDIM);
  float var = fmaxf(q * (1.0f / HDIM) - m * m, 0.f);
  float rs = rsqrtf(var + LN_EPS);
  float y0 = fmaxf(fmaf((o0 - m) * rs, gam[f0], bet[f0]), 0.f);
  float y1 = fmaxf(fmaf((o1 - m) * rs, gam[f1], bet[f1]), 0.f);
  hout[v * HDIM + f0] = __float2half(y0);
  hout[v * HDIM + f1] = __float2half(y1);
}

// ---------------- Aggregation: one wave/node, 8 outstanding half2 row-gathers, fp16 out --------

__global__ __launch_bounds__(256) void agg_kernel(
    const __half* __restrict__ hin, const int* __restrict__ rowptr,
    const int* __restrict__ csr_src, const float* __restrict__ csr_w,
    const float* __restrict__ dinv, __half* __restrict__ agg, int n) {
  int v = blockIdx.x * 4 + (threadIdx.x >> 6);
  if (v >= n) return;
  int lane = threadIdx.x & 63;
  const __half2* h2 = (const __half2*)hin;
  float dv = dinv[v];
  float sw = dv * dv;
  float2 hf = __half22float2(h2[v * 64 + lane]);
  float ax = hf.x * sw, ay = hf.y * sw;  // self-loop
  int e = rowptr[v], e1 = rowptr[v + 1];  // padded: (e1-e) % 8 == 0
  for (; e < e1; e += 8) {
    int s[8];
    float w[8];
#pragma unroll
    for (int u = 0; u < 8; ++u) {
      s[u] = csr_src[e + u];
      w[u] = csr_w[e + u];
    }
    __half2 g[8];
#pragma unroll
    for (int u = 0; u < 8; ++u) g[u] = h2[s[u] * 64 + lane];
#pragma unroll
    for (int u = 0; u < 8; ++u) {
      float2 f = __half22float2(g[u]);
      ax = fmaf(f.x, w[u], ax);
      ay = fmaf(f.y, w[u], ay);
    }
  }
  ((__half2*)agg)[v * 64 + lane] = __floats2half2_rn(ax, ay);
}

// ---------------- MFMA GEMM + LN (+ReLU -> fp16 h | + MFMA head -> out) ----------------
// Block: 256 threads = 4 waves, 64 rows. Wave w: rows v0+w*16 .. +15, all 128 cols.
// mfma_f32_16x16x32_f16: A[m=lane&15][k=(lane>>4)*8+j]; C/D col=lane&15,row=(lane>>4)*4+reg.

__global__ __launch_bounds__(256) void mfma_gemm_kernel(
    const __half* __restrict__ aggh, const __half* __restrict__ Wt,
    const float* __restrict__ bias, const float* __restrict__ gam,
    const float* __restrict__ bet, __half* __restrict__ hout,
    const __half* __restrict__ rW1t, const float* __restrict__ rb1,
    const float* __restrict__ rW2, const float* __restrict__ rb2,
    float* __restrict__ out, int n, int mode) {
  __shared__ __align__(16) __half smem[128 * 136];  // 34 KB: Wt staged; later aliased as 64x136 tile
  int tid = threadIdx.x;
  int v0 = blockIdx.x * 64;
  int lane = tid & 63;
  int wv = tid >> 6;
  int m = lane & 15;   // A-row / B-col / C-col index
  int q = lane >> 4;   // quad

  // Stage Wt (128x128 fp16) -> LDS, row stride 136 (+16B pad: 2-way banks, free).
#pragma unroll
  for (int i = 0; i < 8; ++i) {
    int u = tid + i * 256;  // 2048 units of 16B
    int row = u >> 4, seg = u & 15;
    *(uint4*)&smem[row * 136 + seg * 8] = *(const uint4*)&Wt[row * 128 + seg * 8];
  }

  // A-fragments from global (fp16 agg), 4 k-tiles, clamped rows.
  int row = v0 + wv * 16 + m;
  int rowc = row < n ? row : n - 1;
  const __half* abase = aggh + (size_t)rowc * 128 + q * 8;
  half8 afrag[4];
#pragma unroll
  for (int kt = 0; kt < 4; ++kt) afrag[kt] = *(const half8*)(abase + kt * 32);

  __syncthreads();

  f32x4 acc[8];
#pragma unroll
  for (int c = 0; c < 8; ++c) acc[c] = (f32x4){0.f, 0.f, 0.f, 0.f};
#pragma unroll
  for (int kt = 0; kt < 4; ++kt) {
#pragma unroll
    for (int c = 0; c < 8; ++c) {
      half8 b = *(const half8*)&smem[(c * 16 + m) * 136 + kt * 32 + q * 8];
      acc[c] = __builtin_amdgcn_mfma_f32_16x16x32_f16(afrag[kt], b, acc[c], 0, 0, 0);
    }
  }

  // + bias, then LN per row (rows live in 16-lane groups -> width-16 butterflies).
#pragma unroll
  for (int c = 0; c < 8; ++c) {
    float bcol = bias[c * 16 + m];
#pragma unroll
    for (int r = 0; r < 4; ++r) acc[c][r] += bcol;
  }
  float mean[4], rstd[4];
#pragma unroll
  for (int r = 0; r < 4; ++r) {
    float s = 0.f, q2 = 0.f;
#pragma unroll
    for (int c = 0; c < 8; ++c) {
      float vv = acc[c][r];
      s += vv;
      q2 += vv * vv;
    }
#pragma unroll
    for (int off = 8; off >= 1; off >>= 1) {
      s += __shfl_xor(s, off, 16);
      q2 += __shfl_xor(q2, off, 16);
    }
    float mu = s * (1.f / HDIM);
    float var = fmaxf(q2 * (1.f / HDIM) - mu * mu, 0.f);
    mean[r] = mu;
    rstd[r] = rsqrtf(var + LN_EPS);
  }

  __syncthreads();  // all waves done reading Wt from LDS; alias as output tile
  __half* tile = smem;  // 64 x 136
#pragma unroll
  for (int c = 0; c < 8; ++c) {
    float g = gam[c * 16 + m], bb = bet[c * 16 + m];
#pragma unroll
    for (int r = 0; r < 4; ++r) {
      float y = fmaf((acc[c][r] - mean[r]) * rstd[r], g, bb);
      if (mode == 1) y = fmaxf(y, 0.f);
      tile[(wv * 16 + q * 4 + r) * 136 + c * 16 + m] = __float2half(y);
    }
  }
  __syncthreads();

  if (mode == 1) {
    // Coalesced copy tile -> hout: 64 rows x 128 fp16 = 1024 16B units.
#pragma unroll
    for (int i = 0; i < 4; ++i) {
      int u = tid + i * 256;
      int r = u >> 4, seg = u & 15;
      int v = v0 + r;
      if (v < n) *(uint4*)&hout[(size_t)v * 128 + seg * 8] = *(const uint4*)&tile[r * 136 + seg * 8];
    }
    return;
  }

  // mode 2: fused head, MFMA 128->64 (rW1t from global, L1-hot), ReLU, dot rW2, sigmoid.
  f32x4 hacc[4];
#pragma unroll
  for (int c = 0; c < 4; ++c) hacc[c] = (f32x4){0.f, 0.f, 0.f, 0.f};
#pragma unroll
  for (int kt = 0; kt < 4; ++kt) {
    half8 a = *(const half8*)&tile[(wv * 16 + m) * 136 + kt * 32 + q * 8];
#pragma unroll
    for (int c = 0; c < 4; ++c) {
      half8 b = *(const half8*)&rW1t[(c * 16 + m) * 128 + kt * 32 + q * 8];
      hacc[c] = __builtin_amdgcn_mfma_f32_16x16x32_f16(a, b, hacc[c], 0, 0, 0);
    }
  }
  float p[4] = {0.f, 0.f, 0.f, 0.f};
#pragma unroll
  for (int c = 0; c < 4; ++c) {
    float rb = rb1[c * 16 + m], w2 = rW2[c * 16 + m];
#pragma unroll
    for (int r = 0; r < 4; ++r) {
      float hv = fmaxf(hacc[c][r] + rb, 0.f);
      p[r] = fmaf(hv, w2, p[r]);
    }
  }
#pragma unroll
  for (int r = 0; r < 4; ++r) {
#pragma unroll
    for (int off = 8; off >= 1; off >>= 1) p[r] += __shfl_xor(p[r], off, 16);
  }
  if (m == 0) {
    float rb2v = rb2[0];
#pragma unroll
    for (int r = 0; r < 4; ++r) {
      int v = v0 + wv * 16 + q * 4 + r;
      if (v < n) out[v] = 1.f / (1.f + expf(-(p[r] + rb2v)));
    }
  }
}

// ---------------- Launch ----------------

extern "C" void kernel_launch(void* const* d_in, const int* in_sizes, int n_in,
                              void* d_out, int out_size, void* d_ws, size_t ws_size,
                              hipStream_t stream) {
  const float* x   = (const float*)d_in[0];
  const int*  eidx = (const int*)d_in[1];
  const float* W1  = (const float*)d_in[2];
  const float* b1  = (const float*)d_in[3];
  const float* W2  = (const float*)d_in[4];
  const float* b2  = (const float*)d_in[5];
  const float* W3  = (const float*)d_in[6];
  const float* b3  = (const float*)d_in[7];
  const float* g1  = (const float*)d_in[8];
  const float* be1 = (const float*)d_in[9];
  const float* g2  = (const float*)d_in[10];
  const float* be2 = (const float*)d_in[11];
  const float* g3  = (const float*)d_in[12];
  const float* be3 = (const float*)d_in[13];
  const float* rW1 = (const float*)d_in[14];
  const float* rb1 = (const float*)d_in[15];
  const float* rW2 = (const float*)d_in[16];
  const float* rb2 = (const float*)d_in[17];

  int N = in_sizes[0] / 6;
  int E = in_sizes[1] / 2;
  int Epad = E + 8 * N;
  const int* srcp = eidx;
  const int* dstp = eidx + E;
  float* out = (float*)d_out;

  char* p = (char*)d_ws;
  auto alloc = [&](size_t bytes) -> void* {
    void* r = (void*)p;
    p += (bytes + 255) & ~(size_t)255;
    return r;
  };
  int*    counts   = (int*)alloc((size_t)N * 4);
  int*    rowptr   = (int*)alloc((size_t)(N + 1) * 4);
  int*    cursor   = (int*)alloc((size_t)N * 4);
  float*  dinvp    = (float*)alloc((size_t)N * 4);
  int*    blocksum = (int*)alloc((size_t)1024 * 4);
  int*    csr_src  = (int*)alloc((size_t)Epad * 4);
  float*  csr_w    = (float*)alloc((size_t)Epad * 4);
  __half* h16_a    = (__half*)alloc((size_t)N * HDIM * 2);
  __half* h16_b    = (__half*)alloc((size_t)N * HDIM * 2);
  __half* aggbuf   = (__half*)alloc((size_t)N * HDIM * 2);
  __half* w2t      = (__half*)alloc((size_t)HDIM * HDIM * 2);
  __half* w3t      = (__half*)alloc((size_t)HDIM * HDIM * 2);
  __half* rw1t     = (__half*)alloc((size_t)64 * HDIM * 2);

  int nscan = (N + SCAN_CHUNK - 1) / SCAN_CHUNK;

  hipMemsetAsync(counts, 0, (size_t)N * 4, stream);
  hipMemsetAsync(csr_src, 0, (size_t)Epad * 4, stream);  // pads gather row 0
  hipMemsetAsync(csr_w, 0, (size_t)Epad * 4, stream);    // pads weight 0
  count_kernel<<<(E + 255) / 256, 256, 0, stream>>>(dstp, counts, E);
  dinv_kernel<<<(N + 255) / 256, 256, 0, stream>>>(counts, dinvp, N);
  scan1_kernel<<<nscan, 256, 0, stream>>>(counts, blocksum, N);
  scan2_kernel<<<1, 256, 0, stream>>>(blocksum, nscan);
  scan3_kernel<<<nscan, 256, 0, stream>>>(counts, blocksum, rowptr, cursor, N, nscan);
  fill_kernel<<<(E + 255) / 256, 256, 0, stream>>>(srcp, dstp, cursor, dinvp, csr_src, csr_w, E);
  transpose_h_kernel<<<(HDIM * HDIM + 255) / 256, 256, 0, stream>>>(W2, w2t, HDIM, HDIM);
  transpose_h_kernel<<<(HDIM * HDIM + 255) / 256, 256, 0, stream>>>(W3, w3t, HDIM, HDIM);
  transpose_h_kernel<<<(HDIM * 64 + 255) / 256, 256, 0, stream>>>(rW1, rw1t, HDIM, 64);

  int nw = (N + 3) / 4;   // one wave per node
  int nb = (N + 63) / 64; // 64 rows per MFMA block
  layer1_kernel<<<nw, 256, 0, stream>>>(x, W1, b1, g1, be1, rowptr, csr_src, csr_w, dinvp, h16_a, N);
  agg_kernel<<<nw, 256, 0, stream>>>(h16_a, rowptr, csr_src, csr_w, dinvp, aggbuf, N);
  mfma_gemm_kernel<<<nb, 256, 0, stream>>>(aggbuf, w2t, b2, g2, be2, h16_b,
                                           rw1t, rb1, rW2, rb2, out, N, 1);
  agg_kernel<<<nw, 256, 0, stream>>>(h16_b, rowptr, csr_src, csr_w, dinvp, aggbuf, N);
  mfma_gemm_kernel<<<nb, 256, 0, stream>>>(aggbuf, w3t, b3, g3, be3, h16_b,
                                           rw1t, rb1, rW2, rb2, out, N, 2);
}

// Round 6
// 306.979 us; speedup vs baseline: 2.5245x; 1.0018x over previous
//
#include <hip/hip_runtime.h>
#include <hip/hip_fp16.h>
#include <math.h>

#define HDIM 128
#define LN_EPS 1e-5f
#define SCAN_CHUNK 1024  // elements per scan block (256 threads x 4)

typedef _Float16 half8 __attribute__((ext_vector_type(8)));
typedef float f32x4 __attribute__((ext_vector_type(4)));

// CSR edge record: x = src index, y = weight bits (fp32). One 8B store/load per edge.

// ---------------- CSR build (rows padded to multiples of 8, pad entries {0, 0.0f}) -------------

__global__ void count_kernel(const int* __restrict__ dst, int* __restrict__ counts, int E) {
  int e = blockIdx.x * blockDim.x + threadIdx.x;
  if (e < E) atomicAdd(&counts[dst[e]], 1);
}

__global__ void dinv_kernel(const int* __restrict__ counts, float* __restrict__ dinv, int n) {
  int v = blockIdx.x * blockDim.x + threadIdx.x;
  if (v < n) dinv[v] = rsqrtf((float)(counts[v] + 1));  // +1 self-loop => deg >= 1
}

__global__ __launch_bounds__(256) void scan1_kernel(const int* __restrict__ counts,
                                                    int* __restrict__ blocksum, int n) {
  int base = blockIdx.x * SCAN_CHUNK;
  int tid = threadIdx.x;
  int sum = 0;
#pragma unroll
  for (int j = 0; j < 4; ++j) {
    int i = base + tid * 4 + j;
    if (i < n) sum += (counts[i] + 7) & ~7;
  }
#pragma unroll
  for (int off = 32; off >= 1; off >>= 1) sum += __shfl_xor(sum, off, 64);
  __shared__ int wsum[4];
  if ((tid & 63) == 0) wsum[tid >> 6] = sum;
  __syncthreads();
  if (tid == 0) blocksum[blockIdx.x] = wsum[0] + wsum[1] + wsum[2] + wsum[3];
}

__global__ __launch_bounds__(256) void scan2_kernel(int* __restrict__ blocksum, int nblk) {
  __shared__ int sh[256];
  int tid = threadIdx.x;
  sh[tid] = (tid < nblk) ? blocksum[tid] : 0;
  __syncthreads();
  for (int off = 1; off < 256; off <<= 1) {
    int t = (tid >= off) ? sh[tid - off] : 0;
    __syncthreads();
    sh[tid] += t;
    __syncthreads();
  }
  if (tid < nblk) blocksum[tid] = sh[tid];  // inclusive scan
}

__global__ __launch_bounds__(256) void scan3_kernel(const int* __restrict__ counts,
                                                    const int* __restrict__ blocksum,
                                                    int* __restrict__ rowptr,
                                                    int* __restrict__ cursor, int n, int nblk) {
  int base = blockIdx.x * SCAN_CHUNK;
  int tid = threadIdx.x;
  int c[4];
  int s = 0;
#pragma unroll
  for (int j = 0; j < 4; ++j) {
    int i = base + tid * 4 + j;
    c[j] = (i < n) ? ((counts[i] + 7) & ~7) : 0;
    s += c[j];
  }
  int lane = tid & 63, wid = tid >> 6;
  int incl = s;
#pragma unroll
  for (int off = 1; off < 64; off <<= 1) {
    int t = __shfl_up(incl, off, 64);
    if (lane >= off) incl += t;
  }
  __shared__ int wsum[4];
  if (lane == 63) wsum[wid] = incl;
  __syncthreads();
  int woff = 0;
  for (int w = 0; w < wid; ++w) woff += wsum[w];
  int p = (blockIdx.x == 0 ? 0 : blocksum[blockIdx.x - 1]) + woff + (incl - s);
#pragma unroll
  for (int j = 0; j < 4; ++j) {
    int i = base + tid * 4 + j;
    if (i < n) {
      rowptr[i] = p;
      cursor[i] = p;
    }
    p += c[j];
  }
  if (blockIdx.x == nblk - 1 && tid == 255) rowptr[n] = blocksum[nblk - 1];
}

__global__ void fill_kernel(const int* __restrict__ src, const int* __restrict__ dst,
                            int* __restrict__ cursor, const float* __restrict__ dinv,
                            int2* __restrict__ csr, int E) {
  int e = blockIdx.x * blockDim.x + threadIdx.x;
  if (e < E) {
    int s = src[e], d = dst[e];
    int pos = atomicAdd(&cursor[d], 1);
    int2 rec;
    rec.x = s;
    rec.y = __float_as_int(dinv[s] * dinv[d]);
    csr[pos] = rec;  // single 8B store
  }
}

// ---------------- Weight prep: out (C x R fp16, n-major) = transpose(in (R x C fp32)) ----------

__global__ void transpose_h_kernel(const float* __restrict__ in, __half* __restrict__ out,
                                   int R, int C) {
  int idx = blockIdx.x * 256 + threadIdx.x;
  if (idx < R * C) {
    int nn = idx / R, k = idx % R;
    out[idx] = __float2half(in[k * C + nn]);
  }
}

// ---------------- Layer 1: one wave/node, 6-wide aggregate, 6->128 GEMM + LN + ReLU, fp16 out ----

__global__ __launch_bounds__(256) void layer1_kernel(
    const float* __restrict__ x, const float* __restrict__ W1,
    const float* __restrict__ b1, const float* __restrict__ gam,
    const float* __restrict__ bet, const int* __restrict__ rowptr,
    const int2* __restrict__ csr, const float* __restrict__ dinv,
    __half* __restrict__ hout, int n) {
  int v = blockIdx.x * 4 + (threadIdx.x >> 6);
  if (v >= n) return;
  int lane = threadIdx.x & 63;
  float a[6] = {0.f, 0.f, 0.f, 0.f, 0.f, 0.f};
  int e1 = rowptr[v + 1];
  for (int e = rowptr[v] + lane; e < e1; e += 64) {
    int2 rec = csr[e];
    float w = __int_as_float(rec.y);  // pad entries have w=0
#pragma unroll
    for (int j = 0; j < 6; ++j) a[j] = fmaf(x[rec.x * 6 + j], w, a[j]);
  }
  if (lane == 0) {
    float dv = dinv[v];
    float w = dv * dv;
#pragma unroll
    for (int j = 0; j < 6; ++j) a[j] = fmaf(x[v * 6 + j], w, a[j]);
  }
#pragma unroll
  for (int off = 32; off >= 1; off >>= 1) {
#pragma unroll
    for (int j = 0; j < 6; ++j) a[j] += __shfl_xor(a[j], off, 64);
  }
  int f0 = lane, f1 = lane + 64;
  float o0 = b1[f0], o1 = b1[f1];
#pragma unroll
  for (int j = 0; j < 6; ++j) {
    o0 = fmaf(a[j], W1[j * HDIM + f0], o0);
    o1 = fmaf(a[j], W1[j * HDIM + f1], o1);
  }
  float s = o0 + o1, q = o0 * o0 + o1 * o1;
#pragma unroll
  for (int off = 32; off >= 1; off >>= 1) {
    s += __shfl_xor(s, off, 64);
    q += __shfl_xor(q, off, 64);
  }
  float m = s * (1.0f / HDIM);
  float var = fmaxf(q * (1.0f / HDIM) - m * m, 0.f);
  float rs = rsqrtf(var + LN_EPS);
  float y0 = fmaxf(fmaf((o0 - m) * rs, gam[f0], bet[f0]), 0.f);
  float y1 = fmaxf(fmaf((o1 - m) * rs, gam[f1], bet[f1]), 0.f);
  hout[v * HDIM + f0] = __float2half(y0);
  hout[v * HDIM + f1] = __float2half(y1);
}

// ---------------- Aggregation: one wave/node, 8 outstanding half2 row-gathers, fp16 out --------

__global__ __launch_bounds__(256) void agg_kernel(
    const __half* __restrict__ hin, const int* __restrict__ rowptr,
    const int2* __restrict__ csr, const float* __restrict__ dinv,
    __half* __restrict__ agg, int n) {
  int v = blockIdx.x * 4 + (threadIdx.x >> 6);
  if (v >= n) return;
  int lane = threadIdx.x & 63;
  const __half2* h2 = (const __half2*)hin;
  float dv = dinv[v];
  float sw = dv * dv;
  float2 hf = __half22float2(h2[v * 64 + lane]);
  float ax = hf.x * sw, ay = hf.y * sw;  // self-loop
  int e = rowptr[v], e1 = rowptr[v + 1];  // padded: (e1-e) % 8 == 0
  for (; e < e1; e += 8) {
    int2 rec[8];
#pragma unroll
    for (int u = 0; u < 8; ++u) rec[u] = csr[e + u];
    __half2 g[8];
#pragma unroll
    for (int u = 0; u < 8; ++u) g[u] = h2[rec[u].x * 64 + lane];
#pragma unroll
    for (int u = 0; u < 8; ++u) {
      float2 f = __half22float2(g[u]);
      float w = __int_as_float(rec[u].y);
      ax = fmaf(f.x, w, ax);
      ay = fmaf(f.y, w, ay);
    }
  }
  ((__half2*)agg)[v * 64 + lane] = __floats2half2_rn(ax, ay);
}

// ---------------- MFMA GEMM + LN (+ReLU -> fp16 h | + MFMA head -> out) ----------------
// Block: 256 threads = 4 waves, 64 rows. Wave w: rows v0+w*16 .. +15, all 128 cols.
// mfma_f32_16x16x32_f16: A[m=lane&15][k=(lane>>4)*8+j]; C/D col=lane&15,row=(lane>>4)*4+reg.

__global__ __launch_bounds__(256) void mfma_gemm_kernel(
    const __half* __restrict__ aggh, const __half* __restrict__ Wt,
    const float* __restrict__ bias, const float* __restrict__ gam,
    const float* __restrict__ bet, __half* __restrict__ hout,
    const __half* __restrict__ rW1t, const float* __restrict__ rb1,
    const float* __restrict__ rW2, const float* __restrict__ rb2,
    float* __restrict__ out, int n, int mode) {
  __shared__ __align__(16) __half smem[128 * 136];  // 34 KB: Wt staged; later aliased as 64x136 tile
  int tid = threadIdx.x;
  int v0 = blockIdx.x * 64;
  int lane = tid & 63;
  int wv = tid >> 6;
  int m = lane & 15;   // A-row / B-col / C-col index
  int q = lane >> 4;   // quad

  // Stage Wt (128x128 fp16) -> LDS, row stride 136 (+16B pad: 2-way banks, free).
#pragma unroll
  for (int i = 0; i < 8; ++i) {
    int u = tid + i * 256;  // 2048 units of 16B
    int row = u >> 4, seg = u & 15;
    *(uint4*)&smem[row * 136 + seg * 8] = *(const uint4*)&Wt[row * 128 + seg * 8];
  }

  // A-fragments from global (fp16 agg), 4 k-tiles, clamped rows.
  int row = v0 + wv * 16 + m;
  int rowc = row < n ? row : n - 1;
  const __half* abase = aggh + (size_t)rowc * 128 + q * 8;
  half8 afrag[4];
#pragma unroll
  for (int kt = 0; kt < 4; ++kt) afrag[kt] = *(const half8*)(abase + kt * 32);

  __syncthreads();

  f32x4 acc[8];
#pragma unroll
  for (int c = 0; c < 8; ++c) acc[c] = (f32x4){0.f, 0.f, 0.f, 0.f};
#pragma unroll
  for (int kt = 0; kt < 4; ++kt) {
#pragma unroll
    for (int c = 0; c < 8; ++c) {
      half8 b = *(const half8*)&smem[(c * 16 + m) * 136 + kt * 32 + q * 8];
      acc[c] = __builtin_amdgcn_mfma_f32_16x16x32_f16(afrag[kt], b, acc[c], 0, 0, 0);
    }
  }

  // + bias, then LN per row (rows live in 16-lane groups -> width-16 butterflies).
#pragma unroll
  for (int c = 0; c < 8; ++c) {
    float bcol = bias[c * 16 + m];
#pragma unroll
    for (int r = 0; r < 4; ++r) acc[c][r] += bcol;
  }
  float mean[4], rstd[4];
#pragma unroll
  for (int r = 0; r < 4; ++r) {
    float s = 0.f, q2 = 0.f;
#pragma unroll
    for (int c = 0; c < 8; ++c) {
      float vv = acc[c][r];
      s += vv;
      q2 += vv * vv;
    }
#pragma unroll
    for (int off = 8; off >= 1; off >>= 1) {
      s += __shfl_xor(s, off, 16);
      q2 += __shfl_xor(q2, off, 16);
    }
    float mu = s * (1.f / HDIM);
    float var = fmaxf(q2 * (1.f / HDIM) - mu * mu, 0.f);
    mean[r] = mu;
    rstd[r] = rsqrtf(var + LN_EPS);
  }

  __syncthreads();  // all waves done reading Wt from LDS; alias as output tile
  __half* tile = smem;  // 64 x 136
#pragma unroll
  for (int c = 0; c < 8; ++c) {
    float g = gam[c * 16 + m], bb = bet[c * 16 + m];
#pragma unroll
    for (int r = 0; r < 4; ++r) {
      float y = fmaf((acc[c][r] - mean[r]) * rstd[r], g, bb);
      if (mode == 1) y = fmaxf(y, 0.f);
      tile[(wv * 16 + q * 4 + r) * 136 + c * 16 + m] = __float2half(y);
    }
  }
  __syncthreads();

  if (mode == 1) {
    // Coalesced copy tile -> hout: 64 rows x 128 fp16 = 1024 16B units.
#pragma unroll
    for (int i = 0; i < 4; ++i) {
      int u = tid + i * 256;
      int r = u >> 4, seg = u & 15;
      int v = v0 + r;
      if (v < n) *(uint4*)&hout[(size_t)v * 128 + seg * 8] = *(const uint4*)&tile[r * 136 + seg * 8];
    }
    return;
  }

  // mode 2: fused head, MFMA 128->64 (rW1t from global, L1-hot), ReLU, dot rW2, sigmoid.
  f32x4 hacc[4];
#pragma unroll
  for (int c = 0; c < 4; ++c) hacc[c] = (f32x4){0.f, 0.f, 0.f, 0.f};
#pragma unroll
  for (int kt = 0; kt < 4; ++kt) {
    half8 a = *(const half8*)&tile[(wv * 16 + m) * 136 + kt * 32 + q * 8];
#pragma unroll
    for (int c = 0; c < 4; ++c) {
      half8 b = *(const half8*)&rW1t[(c * 16 + m) * 128 + kt * 32 + q * 8];
      hacc[c] = __builtin_amdgcn_mfma_f32_16x16x32_f16(a, b, hacc[c], 0, 0, 0);
    }
  }
  float p[4] = {0.f, 0.f, 0.f, 0.f};
#pragma unroll
  for (int c = 0; c < 4; ++c) {
    float rb = rb1[c * 16 + m], w2 = rW2[c * 16 + m];
#pragma unroll
    for (int r = 0; r < 4; ++r) {
      float hv = fmaxf(hacc[c][r] + rb, 0.f);
      p[r] = fmaf(hv, w2, p[r]);
    }
  }
#pragma unroll
  for (int r = 0; r < 4; ++r) {
#pragma unroll
    for (int off = 8; off >= 1; off >>= 1) p[r] += __shfl_xor(p[r], off, 16);
  }
  if (m == 0) {
    float rb2v = rb2[0];
#pragma unroll
    for (int r = 0; r < 4; ++r) {
      int v = v0 + wv * 16 + q * 4 + r;
      if (v < n) out[v] = 1.f / (1.f + expf(-(p[r] + rb2v)));
    }
  }
}

// ---------------- Launch ----------------

extern "C" void kernel_launch(void* const* d_in, const int* in_sizes, int n_in,
                              void* d_out, int out_size, void* d_ws, size_t ws_size,
                              hipStream_t stream) {
  const float* x   = (const float*)d_in[0];
  const int*  eidx = (const int*)d_in[1];
  const float* W1  = (const float*)d_in[2];
  const float* b1  = (const float*)d_in[3];
  const float* W2  = (const float*)d_in[4];
  const float* b2  = (const float*)d_in[5];
  const float* W3  = (const float*)d_in[6];
  const float* b3  = (const float*)d_in[7];
  const float* g1  = (const float*)d_in[8];
  const float* be1 = (const float*)d_in[9];
  const float* g2  = (const float*)d_in[10];
  const float* be2 = (const float*)d_in[11];
  const float* g3  = (const float*)d_in[12];
  const float* be3 = (const float*)d_in[13];
  const float* rW1 = (const float*)d_in[14];
  const float* rb1 = (const float*)d_in[15];
  const float* rW2 = (const float*)d_in[16];
  const float* rb2 = (const float*)d_in[17];

  int N = in_sizes[0] / 6;
  int E = in_sizes[1] / 2;
  int Epad = E + 8 * N;
  const int* srcp = eidx;
  const int* dstp = eidx + E;
  float* out = (float*)d_out;

  char* p = (char*)d_ws;
  auto alloc = [&](size_t bytes) -> void* {
    void* r = (void*)p;
    p += (bytes + 255) & ~(size_t)255;
    return r;
  };
  int*    counts   = (int*)alloc((size_t)N * 4);
  int*    rowptr   = (int*)alloc((size_t)(N + 1) * 4);
  int*    cursor   = (int*)alloc((size_t)N * 4);
  float*  dinvp    = (float*)alloc((size_t)N * 4);
  int*    blocksum = (int*)alloc((size_t)1024 * 4);
  int2*   csr      = (int2*)alloc((size_t)Epad * 8);
  __half* h16_a    = (__half*)alloc((size_t)N * HDIM * 2);
  __half* h16_b    = (__half*)alloc((size_t)N * HDIM * 2);
  __half* aggbuf   = (__half*)alloc((size_t)N * HDIM * 2);
  __half* w2t      = (__half*)alloc((size_t)HDIM * HDIM * 2);
  __half* w3t      = (__half*)alloc((size_t)HDIM * HDIM * 2);
  __half* rw1t     = (__half*)alloc((size_t)64 * HDIM * 2);

  int nscan = (N + SCAN_CHUNK - 1) / SCAN_CHUNK;

  hipMemsetAsync(counts, 0, (size_t)N * 4, stream);
  hipMemsetAsync(csr, 0, (size_t)Epad * 8, stream);  // pad entries {src=0, w=0.0f}
  count_kernel<<<(E + 255) / 256, 256, 0, stream>>>(dstp, counts, E);
  dinv_kernel<<<(N + 255) / 256, 256, 0, stream>>>(counts, dinvp, N);
  scan1_kernel<<<nscan, 256, 0, stream>>>(counts, blocksum, N);
  scan2_kernel<<<1, 256, 0, stream>>>(blocksum, nscan);
  scan3_kernel<<<nscan, 256, 0, stream>>>(counts, blocksum, rowptr, cursor, N, nscan);
  fill_kernel<<<(E + 255) / 256, 256, 0, stream>>>(srcp, dstp, cursor, dinvp, csr, E);
  transpose_h_kernel<<<(HDIM * HDIM + 255) / 256, 256, 0, stream>>>(W2, w2t, HDIM, HDIM);
  transpose_h_kernel<<<(HDIM * HDIM + 255) / 256, 256, 0, stream>>>(W3, w3t, HDIM, HDIM);
  transpose_h_kernel<<<(HDIM * 64 + 255) / 256, 256, 0, stream>>>(rW1, rw1t, HDIM, 64);

  int nw = (N + 3) / 4;   // one wave per node
  int nb = (N + 63) / 64; // 64 rows per MFMA block
  layer1_kernel<<<nw, 256, 0, stream>>>(x, W1, b1, g1, be1, rowptr, csr, dinvp, h16_a, N);
  agg_kernel<<<nw, 256, 0, stream>>>(h16_a, rowptr, csr, dinvp, aggbuf, N);
  mfma_gemm_kernel<<<nb, 256, 0, stream>>>(aggbuf, w2t, b2, g2, be2, h16_b,
                                           rw1t, rb1, rW2, rb2, out, N, 1);
  agg_kernel<<<nw, 256, 0, stream>>>(h16_b, rowptr, csr, dinvp, aggbuf, N);
  mfma_gemm_kernel<<<nb, 256, 0, stream>>>(aggbuf, w3t, b3, g3, be3, h16_b,
                                           rw1t, rb1, rW2, rb2, out, N, 2);
}

// Round 7
// 305.295 us; speedup vs baseline: 2.5384x; 1.0055x over previous
//
#include <hip/hip_runtime.h>
#include <hip/hip_fp16.h>
#include <math.h>

#define HDIM 128
#define LN_EPS 1e-5f
#define SCAN_CHUNK 1024  // elements per scan block (256 threads x 4)

typedef _Float16 half8 __attribute__((ext_vector_type(8)));
typedef float f32x4 __attribute__((ext_vector_type(4)));

// Weights are folded into node features: h'[v] = dinv[v] * h[v], so
// agg[v] = dinv[v] * (sum_{s in N(v)} h'[s] + h'[v]).  CSR stores ONLY the
// 4-byte src index per edge; no padding, no weight.

// ---------------- CSR build ----------------

__global__ void count_kernel(const int* __restrict__ dst, int* __restrict__ counts, int E) {
  int e = blockIdx.x * blockDim.x + threadIdx.x;
  if (e < E) atomicAdd(&counts[dst[e]], 1);
}

// scan1 also computes dinv (reads counts anyway).
__global__ __launch_bounds__(256) void scan1_kernel(const int* __restrict__ counts,
                                                    int* __restrict__ blocksum,
                                                    float* __restrict__ dinv, int n) {
  int base = blockIdx.x * SCAN_CHUNK;
  int tid = threadIdx.x;
  int sum = 0;
#pragma unroll
  for (int j = 0; j < 4; ++j) {
    int i = base + tid * 4 + j;
    if (i < n) {
      int c = counts[i];
      sum += c;
      dinv[i] = rsqrtf((float)(c + 1));  // +1 self-loop
    }
  }
#pragma unroll
  for (int off = 32; off >= 1; off >>= 1) sum += __shfl_xor(sum, off, 64);
  __shared__ int wsum[4];
  if ((tid & 63) == 0) wsum[tid >> 6] = sum;
  __syncthreads();
  if (tid == 0) blocksum[blockIdx.x] = wsum[0] + wsum[1] + wsum[2] + wsum[3];
}

__global__ __launch_bounds__(256) void scan2_kernel(int* __restrict__ blocksum, int nblk) {
  __shared__ int sh[256];
  int tid = threadIdx.x;
  sh[tid] = (tid < nblk) ? blocksum[tid] : 0;
  __syncthreads();
  for (int off = 1; off < 256; off <<= 1) {
    int t = (tid >= off) ? sh[tid - off] : 0;
    __syncthreads();
    sh[tid] += t;
    __syncthreads();
  }
  if (tid < nblk) blocksum[tid] = sh[tid];  // inclusive scan
}

__global__ __launch_bounds__(256) void scan3_kernel(const int* __restrict__ counts,
                                                    const int* __restrict__ blocksum,
                                                    int* __restrict__ rowptr,
                                                    int* __restrict__ cursor, int n, int nblk) {
  int base = blockIdx.x * SCAN_CHUNK;
  int tid = threadIdx.x;
  int c[4];
  int s = 0;
#pragma unroll
  for (int j = 0; j < 4; ++j) {
    int i = base + tid * 4 + j;
    c[j] = (i < n) ? counts[i] : 0;
    s += c[j];
  }
  int lane = tid & 63, wid = tid >> 6;
  int incl = s;
#pragma unroll
  for (int off = 1; off < 64; off <<= 1) {
    int t = __shfl_up(incl, off, 64);
    if (lane >= off) incl += t;
  }
  __shared__ int wsum[4];
  if (lane == 63) wsum[wid] = incl;
  __syncthreads();
  int woff = 0;
  for (int w = 0; w < wid; ++w) woff += wsum[w];
  int p = (blockIdx.x == 0 ? 0 : blocksum[blockIdx.x - 1]) + woff + (incl - s);
#pragma unroll
  for (int j = 0; j < 4; ++j) {
    int i = base + tid * 4 + j;
    if (i < n) {
      rowptr[i] = p;
      cursor[i] = p;
    }
    p += c[j];
  }
  if (blockIdx.x == nblk - 1 && tid == 255) rowptr[n] = blocksum[nblk - 1];
}

__global__ void fill_kernel(const int* __restrict__ src, const int* __restrict__ dst,
                            int* __restrict__ cursor, int* __restrict__ csr, int E) {
  int e = blockIdx.x * blockDim.x + threadIdx.x;
  if (e < E) {
    int pos = atomicAdd(&cursor[dst[e]], 1);
    csr[pos] = src[e];  // single 4B store
  }
}

// ---------------- Prep: x' = dinv*x ; fp16-transposed weights (one launch) ----------------

__global__ void prescale_x_kernel(const float* __restrict__ x, const float* __restrict__ dinv,
                                  float* __restrict__ xs, int n) {
  int idx = blockIdx.x * 256 + threadIdx.x;
  if (idx < n * 6) xs[idx] = x[idx] * dinv[idx / 6];
}

__global__ void prep_weights_kernel(const float* __restrict__ W2, const float* __restrict__ W3,
                                    const float* __restrict__ rW1, __half* __restrict__ w2t,
                                    __half* __restrict__ w3t, __half* __restrict__ rw1t) {
  int idx = blockIdx.x * 256 + threadIdx.x;
  if (idx < 16384) {
    int nn = idx >> 7, k = idx & 127;
    w2t[idx] = __float2half(W2[k * 128 + nn]);
  } else if (idx < 32768) {
    int i = idx - 16384;
    int nn = i >> 7, k = i & 127;
    w3t[i] = __float2half(W3[k * 128 + nn]);
  } else if (idx < 40960) {
    int i = idx - 32768;
    int nn = i >> 7, k = i & 127;
    rw1t[i] = __float2half(rW1[k * 64 + nn]);
  }
}

// ---------------- Layer 1: one wave/node; sum x'[s], scale, 6->128 GEMM + LN + ReLU ----------

__global__ __launch_bounds__(256) void layer1_kernel(
    const float* __restrict__ xs, const float* __restrict__ W1,
    const float* __restrict__ b1, const float* __restrict__ gam,
    const float* __restrict__ bet, const int* __restrict__ rowptr,
    const int* __restrict__ csr, const float* __restrict__ dinv,
    __half* __restrict__ hout, int n) {
  int v = blockIdx.x * 4 + (threadIdx.x >> 6);
  if (v >= n) return;
  int lane = threadIdx.x & 63;
  float a[6] = {0.f, 0.f, 0.f, 0.f, 0.f, 0.f};
  int e1 = rowptr[v + 1];
  for (int e = rowptr[v] + lane; e < e1; e += 64) {
    int s = csr[e];
#pragma unroll
    for (int j = 0; j < 6; ++j) a[j] += xs[s * 6 + j];
  }
  if (lane == 0) {
#pragma unroll
    for (int j = 0; j < 6; ++j) a[j] += xs[v * 6 + j];  // self-loop: + x'[v]
  }
#pragma unroll
  for (int off = 32; off >= 1; off >>= 1) {
#pragma unroll
    for (int j = 0; j < 6; ++j) a[j] += __shfl_xor(a[j], off, 64);
  }
  float dv = dinv[v];
#pragma unroll
  for (int j = 0; j < 6; ++j) a[j] *= dv;  // agg = dinv[v] * sum
  int f0 = lane, f1 = lane + 64;
  float o0 = b1[f0], o1 = b1[f1];
#pragma unroll
  for (int j = 0; j < 6; ++j) {
    o0 = fmaf(a[j], W1[j * HDIM + f0], o0);
    o1 = fmaf(a[j], W1[j * HDIM + f1], o1);
  }
  float s = o0 + o1, q = o0 * o0 + o1 * o1;
#pragma unroll
  for (int off = 32; off >= 1; off >>= 1) {
    s += __shfl_xor(s, off, 64);
    q += __shfl_xor(q, off, 64);
  }
  float m = s * (1.0f / HDIM);
  float var = fmaxf(q * (1.0f / HDIM) - m * m, 0.f);
  float rs = rsqrtf(var + LN_EPS);
  float y0 = fmaxf(fmaf((o0 - m) * rs, gam[f0], bet[f0]), 0.f);
  float y1 = fmaxf(fmaf((o1 - m) * rs, gam[f1], bet[f1]), 0.f);
  // store h' = dinv * h
  hout[v * HDIM + f0] = __float2half(y0 * dv);
  hout[v * HDIM + f1] = __float2half(y1 * dv);
}

// ---------------- Aggregation: one wave/node, 8 outstanding gathers, masked tail ------------

__global__ __launch_bounds__(256) void agg_kernel(
    const __half* __restrict__ hin, const int* __restrict__ rowptr,
    const int* __restrict__ csr, const float* __restrict__ dinv,
    __half* __restrict__ agg, int n) {
  int v = blockIdx.x * 4 + (threadIdx.x >> 6);
  if (v >= n) return;
  int lane = threadIdx.x & 63;
  const __half2* h2 = (const __half2*)hin;
  float2 hf = __half22float2(h2[v * 64 + lane]);
  float ax = hf.x, ay = hf.y;  // self-loop: + h'[v]
  int e0 = rowptr[v], e1 = rowptr[v + 1];
  for (int e = e0; e < e1; e += 8) {
    int idx[8];
    bool mk[8];
#pragma unroll
    for (int u = 0; u < 8; ++u) {
      int ee = e + u;
      mk[u] = ee < e1;
      idx[u] = csr[mk[u] ? ee : e1 - 1];
    }
    __half2 g[8];
#pragma unroll
    for (int u = 0; u < 8; ++u) g[u] = h2[idx[u] * 64 + lane];
#pragma unroll
    for (int u = 0; u < 8; ++u) {
      float2 f = __half22float2(g[u]);
      ax += mk[u] ? f.x : 0.f;
      ay += mk[u] ? f.y : 0.f;
    }
  }
  float dv = dinv[v];
  ((__half2*)agg)[v * 64 + lane] = __floats2half2_rn(ax * dv, ay * dv);
}

// ---------------- MFMA GEMM + LN (+ReLU -> fp16 h' | + MFMA head -> out) ----------------
// Block: 256 threads = 4 waves, 64 rows. Wave w: rows v0+w*16 .. +15, all 128 cols.
// mfma_f32_16x16x32_f16: A[m=lane&15][k=(lane>>4)*8+j]; C/D col=lane&15,row=(lane>>4)*4+reg.

__global__ __launch_bounds__(256) void mfma_gemm_kernel(
    const __half* __restrict__ aggh, const __half* __restrict__ Wt,
    const float* __restrict__ bias, const float* __restrict__ gam,
    const float* __restrict__ bet, const float* __restrict__ dinv,
    __half* __restrict__ hout,
    const __half* __restrict__ rW1t, const float* __restrict__ rb1,
    const float* __restrict__ rW2, const float* __restrict__ rb2,
    float* __restrict__ out, int n, int mode) {
  __shared__ __align__(16) __half smem[128 * 136];  // 34 KB: Wt staged; later aliased as tile
  int tid = threadIdx.x;
  int v0 = blockIdx.x * 64;
  int lane = tid & 63;
  int wv = tid >> 6;
  int m = lane & 15;   // A-row / B-col / C-col index
  int q = lane >> 4;   // quad

  // Stage Wt (128x128 fp16) -> LDS, row stride 136 (+16B pad: 2-way banks, free).
#pragma unroll
  for (int i = 0; i < 8; ++i) {
    int u = tid + i * 256;  // 2048 units of 16B
    int row = u >> 4, seg = u & 15;
    *(uint4*)&smem[row * 136 + seg * 8] = *(const uint4*)&Wt[row * 128 + seg * 8];
  }

  // A-fragments from global (fp16 agg), 4 k-tiles, clamped rows.
  int row = v0 + wv * 16 + m;
  int rowc = row < n ? row : n - 1;
  const __half* abase = aggh + (size_t)rowc * 128 + q * 8;
  half8 afrag[4];
#pragma unroll
  for (int kt = 0; kt < 4; ++kt) afrag[kt] = *(const half8*)(abase + kt * 32);

  __syncthreads();

  f32x4 acc[8];
#pragma unroll
  for (int c = 0; c < 8; ++c) acc[c] = (f32x4){0.f, 0.f, 0.f, 0.f};
#pragma unroll
  for (int kt = 0; kt < 4; ++kt) {
#pragma unroll
    for (int c = 0; c < 8; ++c) {
      half8 b = *(const half8*)&smem[(c * 16 + m) * 136 + kt * 32 + q * 8];
      acc[c] = __builtin_amdgcn_mfma_f32_16x16x32_f16(afrag[kt], b, acc[c], 0, 0, 0);
    }
  }

  // + bias, then LN per row (rows live in 16-lane groups -> width-16 butterflies).
#pragma unroll
  for (int c = 0; c < 8; ++c) {
    float bcol = bias[c * 16 + m];
#pragma unroll
    for (int r = 0; r < 4; ++r) acc[c][r] += bcol;
  }
  float mean[4], rstd[4], dvr[4];
#pragma unroll
  for (int r = 0; r < 4; ++r) {
    float s = 0.f, q2 = 0.f;
#pragma unroll
    for (int c = 0; c < 8; ++c) {
      float vv = acc[c][r];
      s += vv;
      q2 += vv * vv;
    }
#pragma unroll
    for (int off = 8; off >= 1; off >>= 1) {
      s += __shfl_xor(s, off, 16);
      q2 += __shfl_xor(q2, off, 16);
    }
    float mu = s * (1.f / HDIM);
    float var = fmaxf(q2 * (1.f / HDIM) - mu * mu, 0.f);
    mean[r] = mu;
    rstd[r] = rsqrtf(var + LN_EPS);
    int vr = v0 + wv * 16 + q * 4 + r;
    dvr[r] = (mode == 1 && vr < n) ? dinv[vr] : 1.f;  // h' scale for next layer's agg
  }

  __syncthreads();  // all waves done reading Wt from LDS; alias as output tile
  __half* tile = smem;  // 64 x 136
#pragma unroll
  for (int c = 0; c < 8; ++c) {
    float g = gam[c * 16 + m], bb = bet[c * 16 + m];
#pragma unroll
    for (int r = 0; r < 4; ++r) {
      float y = fmaf((acc[c][r] - mean[r]) * rstd[r], g, bb);
      if (mode == 1) y = fmaxf(y, 0.f) * dvr[r];
      tile[(wv * 16 + q * 4 + r) * 136 + c * 16 + m] = __float2half(y);
    }
  }
  __syncthreads();

  if (mode == 1) {
    // Coalesced copy tile -> hout: 64 rows x 128 fp16 = 1024 16B units.
#pragma unroll
    for (int i = 0; i < 4; ++i) {
      int u = tid + i * 256;
      int r = u >> 4, seg = u & 15;
      int v = v0 + r;
      if (v < n) *(uint4*)&hout[(size_t)v * 128 + seg * 8] = *(const uint4*)&tile[r * 136 + seg * 8];
    }
    return;
  }

  // mode 2: fused head, MFMA 128->64 (rW1t from global, L1-hot), ReLU, dot rW2, sigmoid.
  f32x4 hacc[4];
#pragma unroll
  for (int c = 0; c < 4; ++c) hacc[c] = (f32x4){0.f, 0.f, 0.f, 0.f};
#pragma unroll
  for (int kt = 0; kt < 4; ++kt) {
    half8 a = *(const half8*)&tile[(wv * 16 + m) * 136 + kt * 32 + q * 8];
#pragma unroll
    for (int c = 0; c < 4; ++c) {
      half8 b = *(const half8*)&rW1t[(c * 16 + m) * 128 + kt * 32 + q * 8];
      hacc[c] = __builtin_amdgcn_mfma_f32_16x16x32_f16(a, b, hacc[c], 0, 0, 0);
    }
  }
  float p[4] = {0.f, 0.f, 0.f, 0.f};
#pragma unroll
  for (int c = 0; c < 4; ++c) {
    float rb = rb1[c * 16 + m], w2 = rW2[c * 16 + m];
#pragma unroll
    for (int r = 0; r < 4; ++r) {
      float hv = fmaxf(hacc[c][r] + rb, 0.f);
      p[r] = fmaf(hv, w2, p[r]);
    }
  }
#pragma unroll
  for (int r = 0; r < 4; ++r) {
#pragma unroll
    for (int off = 8; off >= 1; off >>= 1) p[r] += __shfl_xor(p[r], off, 16);
  }
  if (m == 0) {
    float rb2v = rb2[0];
#pragma unroll
    for (int r = 0; r < 4; ++r) {
      int v = v0 + wv * 16 + q * 4 + r;
      if (v < n) out[v] = 1.f / (1.f + expf(-(p[r] + rb2v)));
    }
  }
}

// ---------------- Launch ----------------

extern "C" void kernel_launch(void* const* d_in, const int* in_sizes, int n_in,
                              void* d_out, int out_size, void* d_ws, size_t ws_size,
                              hipStream_t stream) {
  const float* x   = (const float*)d_in[0];
  const int*  eidx = (const int*)d_in[1];
  const float* W1  = (const float*)d_in[2];
  const float* b1  = (const float*)d_in[3];
  const float* W2  = (const float*)d_in[4];
  const float* b2  = (const float*)d_in[5];
  const float* W3  = (const float*)d_in[6];
  const float* b3  = (const float*)d_in[7];
  const float* g1  = (const float*)d_in[8];
  const float* be1 = (const float*)d_in[9];
  const float* g2  = (const float*)d_in[10];
  const float* be2 = (const float*)d_in[11];
  const float* g3  = (const float*)d_in[12];
  const float* be3 = (const float*)d_in[13];
  const float* rW1 = (const float*)d_in[14];
  const float* rb1 = (const float*)d_in[15];
  const float* rW2 = (const float*)d_in[16];
  const float* rb2 = (const float*)d_in[17];

  int N = in_sizes[0] / 6;
  int E = in_sizes[1] / 2;
  const int* srcp = eidx;
  const int* dstp = eidx + E;
  float* out = (float*)d_out;

  char* p = (char*)d_ws;
  auto alloc = [&](size_t bytes) -> void* {
    void* r = (void*)p;
    p += (bytes + 255) & ~(size_t)255;
    return r;
  };
  int*    counts   = (int*)alloc((size_t)N * 4);
  int*    rowptr   = (int*)alloc((size_t)(N + 1) * 4);
  int*    cursor   = (int*)alloc((size_t)N * 4);
  float*  dinvp    = (float*)alloc((size_t)N * 4);
  int*    blocksum = (int*)alloc((size_t)1024 * 4);
  int*    csr      = (int*)alloc((size_t)E * 4);
  float*  xs       = (float*)alloc((size_t)N * 6 * 4);
  __half* h16_a    = (__half*)alloc((size_t)N * HDIM * 2);
  __half* h16_b    = (__half*)alloc((size_t)N * HDIM * 2);
  __half* aggbuf   = (__half*)alloc((size_t)N * HDIM * 2);
  __half* w2t      = (__half*)alloc((size_t)HDIM * HDIM * 2);
  __half* w3t      = (__half*)alloc((size_t)HDIM * HDIM * 2);
  __half* rw1t     = (__half*)alloc((size_t)64 * HDIM * 2);

  int nscan = (N + SCAN_CHUNK - 1) / SCAN_CHUNK;

  hipMemsetAsync(counts, 0, (size_t)N * 4, stream);
  count_kernel<<<(E + 255) / 256, 256, 0, stream>>>(dstp, counts, E);
  scan1_kernel<<<nscan, 256, 0, stream>>>(counts, blocksum, dinvp, N);
  scan2_kernel<<<1, 256, 0, stream>>>(blocksum, nscan);
  scan3_kernel<<<nscan, 256, 0, stream>>>(counts, blocksum, rowptr, cursor, N, nscan);
  fill_kernel<<<(E + 255) / 256, 256, 0, stream>>>(srcp, dstp, cursor, csr, E);
  prescale_x_kernel<<<(N * 6 + 255) / 256, 256, 0, stream>>>(x, dinvp, xs, N);
  prep_weights_kernel<<<(40960 + 255) / 256, 256, 0, stream>>>(W2, W3, rW1, w2t, w3t, rw1t);

  int nw = (N + 3) / 4;   // one wave per node
  int nb = (N + 63) / 64; // 64 rows per MFMA block
  layer1_kernel<<<nw, 256, 0, stream>>>(xs, W1, b1, g1, be1, rowptr, csr, dinvp, h16_a, N);
  agg_kernel<<<nw, 256, 0, stream>>>(h16_a, rowptr, csr, dinvp, aggbuf, N);
  mfma_gemm_kernel<<<nb, 256, 0, stream>>>(aggbuf, w2t, b2, g2, be2, dinvp, h16_b,
                                           rw1t, rb1, rW2, rb2, out, N, 1);
  agg_kernel<<<nw, 256, 0, stream>>>(h16_b, rowptr, csr, dinvp, aggbuf, N);
  mfma_gemm_kernel<<<nb, 256, 0, stream>>>(aggbuf, w3t, b3, g3, be3, dinvp, h16_b,
                                           rw1t, rb1, rW2, rb2, out, N, 2);
}